// Round 1
// baseline (11549.848 us; speedup 1.0000x reference)
//
#include <hip/hip_runtime.h>
#include <math.h>

// ---------------------------------------------------------------------------
// ArcHybridLSTM forward on MI355X — round 1: correct fp32 baseline.
// Pipeline:
//   1. embed:       ivec[B,S,160] = cat(wlookup[word], plookup[pos])
//   2. gemm xg1f/1b: xg = ivec @ Wih^T + (bih+bhh)        [B,S,1024]
//   3. lstm_rec L1:  -> vec1[B,S,512]  (f cols 0:256, b cols 256:512)
//   4. gemm xg2f/2b: xg = vec1 @ Wih2^T + bias
//   5. lstm_rec L2:  -> vec2[B,S,512]
//   6. gather-GEMM:  hidcat[B*T,1024] = tanh(feats @ [hidLayer|rhidLayer]^T + b)
//                    (gather of vec2 rows fused into A-tile load)
//   7. small GEMMs:  out[B,T,3], rout[B,T,93] -> d_out (concatenated)
// LSTM recurrence: 1 WG (512 thr) per {2 batch rows, direction}; WhhT
// pre-transposed so weight loads are lane-coalesced and L2-resident.
// ---------------------------------------------------------------------------

namespace {
constexpr int kB = 64, kS = 256, kH = 256, kG4 = 1024;   // batch, seq, hidden, 4H
constexpr int kD1 = 160, kLD = 512;                      // ivec dim, LSTM concat dim
constexpr int kFeat = 6144, kSlots = 12;
constexpr int kTok = kB * kS;                            // 16384 rows everywhere
}

// ---------------- embeddings ----------------
__global__ void embed_kernel(const int* __restrict__ wid, const int* __restrict__ pid,
                             const float* __restrict__ wl, const float* __restrict__ pl,
                             float* __restrict__ ivec) {
  int tid = blockIdx.x * blockDim.x + threadIdx.x;  // kTok * 40 float4 chunks
  if (tid >= kTok * 40) return;
  int tok = tid / 40;
  int c = tid - tok * 40;
  float4 v;
  if (c < 32) v = ((const float4*)wl)[(size_t)wid[tok] * 32 + c];
  else        v = ((const float4*)pl)[(size_t)pid[tok] * 8 + (c - 32)];
  ((float4*)ivec)[(size_t)tok * 40 + c] = v;
}

// ---------------- bias sums (bih+bhh per layer/dir) ----------------
__global__ void prep_bias(const float* __restrict__ b0, const float* __restrict__ b1,
                          const float* __restrict__ b2, const float* __restrict__ b3,
                          const float* __restrict__ b4, const float* __restrict__ b5,
                          const float* __restrict__ b6, const float* __restrict__ b7,
                          float* __restrict__ bsum) {
  int tid = blockIdx.x * blockDim.x + threadIdx.x;
  if (tid >= 4 * kG4) return;
  int grp = tid >> 10, i = tid & 1023;
  const float* x; const float* y;
  switch (grp) {
    case 0: x = b0; y = b1; break;
    case 1: x = b2; y = b3; break;
    case 2: x = b4; y = b5; break;
    default: x = b6; y = b7; break;
  }
  bsum[tid] = x[i] + y[i];
}

// ---------------- Whh transpose: [1024][256] -> [256][1024] ----------------
__global__ void transpose_whh(const float* __restrict__ w0, const float* __restrict__ w1,
                              const float* __restrict__ w2, const float* __restrict__ w3,
                              float* __restrict__ out) {
  __shared__ float t[32][33];
  const float* src = (blockIdx.z == 0) ? w0 : (blockIdx.z == 1) ? w1
                    : (blockIdx.z == 2) ? w2 : w3;
  float* dst = out + (size_t)blockIdx.z * (kG4 * kH);
  int x0 = blockIdx.x * 32;  // k   (0..255)
  int y0 = blockIdx.y * 32;  // gate(0..1023)
  int tx = threadIdx.x, ty = threadIdx.y;
#pragma unroll
  for (int i = 0; i < 4; i++)
    t[ty + 8 * i][tx] = src[(size_t)(y0 + ty + 8 * i) * kH + x0 + tx];
  __syncthreads();
#pragma unroll
  for (int i = 0; i < 4; i++)
    dst[(size_t)(x0 + ty + 8 * i) * kG4 + y0 + tx] = t[tx][ty + 8 * i];
}

// ---------------- generic fp32 GEMM: C = act(A @ W^T + bias) ----------------
// A: [16384, K] (lda), or gathered feats when GATHER (vsrc=vec2, fidx).
// W rows n<nsplit from W, else W2[n-nsplit]; same for bias. 128x128x8 tile,
// 256 threads, 8x8 per-thread register tile.
template <bool GATHER, bool TANH>
__global__ __launch_bounds__(256) void gemm_kernel(
    const float* __restrict__ A, int lda,
    const float* __restrict__ W, const float* __restrict__ W2, int nsplit,
    const float* __restrict__ bias, const float* __restrict__ bias2,
    const float* __restrict__ vsrc, const int* __restrict__ fidx,
    float* __restrict__ C, int ldc, int N, int K) {
  __shared__ float As[8][128];
  __shared__ float Bs[8][128];
  const int tid = threadIdx.x;
  const int m0 = blockIdx.y * 128;
  const int n0 = blockIdx.x * 128;
  const int tx = tid & 15, ty = tid >> 4;
  const int lm = tid >> 1;           // 0..127 tile row
  const int lk = (tid & 1) * 4;      // 0 or 4
  float acc[8][8] = {};

  for (int k0 = 0; k0 < K; k0 += 8) {
    float4 av;
    if (GATHER) {
      int m = m0 + lm, k = k0 + lk;
      int slot = k >> 9;
      int idx = fidx[m * kSlots + slot];
      int b = m >> 8;
      av = *(const float4*)(vsrc + ((size_t)((b << 8) + idx) << 9) + (k & 511));
    } else {
      av = *(const float4*)(A + (size_t)(m0 + lm) * lda + k0 + lk);
    }
    const int n = n0 + lm;
    float4 bv = make_float4(0.f, 0.f, 0.f, 0.f);
    if (n < N) {
      const float* Wr = (n < nsplit) ? (W + (size_t)n * K)
                                     : (W2 + (size_t)(n - nsplit) * K);
      bv = *(const float4*)(Wr + k0 + lk);
    }
    __syncthreads();
    As[lk + 0][lm] = av.x; As[lk + 1][lm] = av.y;
    As[lk + 2][lm] = av.z; As[lk + 3][lm] = av.w;
    Bs[lk + 0][lm] = bv.x; Bs[lk + 1][lm] = bv.y;
    Bs[lk + 2][lm] = bv.z; Bs[lk + 3][lm] = bv.w;
    __syncthreads();
#pragma unroll
    for (int kk = 0; kk < 8; kk++) {
      float a[8], b8[8];
      *(float4*)&a[0]  = *(const float4*)&As[kk][ty * 8];
      *(float4*)&a[4]  = *(const float4*)&As[kk][ty * 8 + 4];
      *(float4*)&b8[0] = *(const float4*)&Bs[kk][tx * 8];
      *(float4*)&b8[4] = *(const float4*)&Bs[kk][tx * 8 + 4];
#pragma unroll
      for (int i = 0; i < 8; i++)
#pragma unroll
        for (int j = 0; j < 8; j++)
          acc[i][j] = fmaf(a[i], b8[j], acc[i][j]);
    }
  }
#pragma unroll
  for (int i = 0; i < 8; i++) {
    size_t m = m0 + ty * 8 + i;
#pragma unroll
    for (int j = 0; j < 8; j++) {
      int n = n0 + tx * 8 + j;
      if (n < N) {
        float bb = (n < nsplit) ? bias[n] : bias2[n - nsplit];
        float v = acc[i][j] + bb;
        if (TANH) v = tanhf(v);
        C[m * ldc + n] = v;
      }
    }
  }
}

// ---------------- LSTM recurrence ----------------
// grid 64: wg = dir*32 + pair; each wg owns batch rows {2*pair, 2*pair+1}.
// 512 threads: dot phase thread p -> gates {2p,2p+1} x 2 rows (WhhT float2,
// lane-coalesced, L2-resident); nonlin phase thread q -> (row=q>>8, col=q&255),
// c state in a register, h in LDS laid out [k][row] for float4 broadcast reads.
__global__ __launch_bounds__(512) void lstm_rec_kernel(
    const float* __restrict__ xg_f, const float* __restrict__ xg_b,
    const float* __restrict__ whhT_f, const float* __restrict__ whhT_b,
    float* __restrict__ out /* [B][S][512] */) {
  __shared__ float4 h4[kH / 2];          // 256*2 floats: [k][row0,row1]
  __shared__ float g_lds[2][kG4];
  float* h_lds = (float*)h4;

  const int wid = blockIdx.x;
  const int dir = wid >> 5;
  const int pair = wid & 31;
  const float* xg   = dir ? xg_b  : xg_f;
  const float2* w2  = (const float2*)(dir ? whhT_b : whhT_f);
  const int t = threadIdx.x;
  const int row = t >> 8, col = t & 255;
  const int batch = pair * 2 + row;

  h_lds[t] = 0.f;
  float c_state = 0.f;
  __syncthreads();

  for (int it = 0; it < kS; ++it) {
    const int s = dir ? (kS - 1 - it) : it;
    // ---- dot phase: g[2t],g[2t+1] for both rows ----
    float a00 = 0.f, a10 = 0.f, a01 = 0.f, a11 = 0.f;  // a[gate][rowIdx]
#pragma unroll 8
    for (int k = 0; k < kH; k += 2) {
      float4 h2 = h4[k >> 1];                       // h[k][0],h[k][1],h[k+1][0],h[k+1][1]
      float2 w_0 = w2[(size_t)k * 512 + t];
      float2 w_1 = w2[(size_t)(k + 1) * 512 + t];
      a00 = fmaf(w_0.x, h2.x, a00); a10 = fmaf(w_0.y, h2.x, a10);
      a01 = fmaf(w_0.x, h2.y, a01); a11 = fmaf(w_0.y, h2.y, a11);
      a00 = fmaf(w_1.x, h2.z, a00); a10 = fmaf(w_1.y, h2.z, a10);
      a01 = fmaf(w_1.x, h2.w, a01); a11 = fmaf(w_1.y, h2.w, a11);
    }
    ((float2*)&g_lds[0][0])[t] = make_float2(a00, a10);
    ((float2*)&g_lds[1][0])[t] = make_float2(a01, a11);
    __syncthreads();
    // ---- nonlinearity phase ----
    {
      const float* xgrow = xg + ((size_t)(batch * kS + s)) * kG4;
      float gi = g_lds[row][col]        + xgrow[col];
      float gf = g_lds[row][col + 256]  + xgrow[col + 256];
      float gg = g_lds[row][col + 512]  + xgrow[col + 512];
      float go = g_lds[row][col + 768]  + xgrow[col + 768];
      float i_ = 1.f / (1.f + __expf(-gi));
      float f_ = 1.f / (1.f + __expf(-gf));
      float g_ = tanhf(gg);
      float o_ = 1.f / (1.f + __expf(-go));
      c_state = f_ * c_state + i_ * g_;
      float h = o_ * tanhf(c_state);
      h_lds[col * 2 + row] = h;
      out[((size_t)(batch * kS + s)) * kLD + dir * kH + col] = h;
    }
    __syncthreads();
  }
}

// ---------------------------------------------------------------------------
extern "C" void kernel_launch(void* const* d_in, const int* in_sizes, int n_in,
                              void* d_out, int out_size, void* d_ws, size_t ws_size,
                              hipStream_t stream) {
  const int*   word_ids = (const int*)d_in[0];
  const int*   pos_ids  = (const int*)d_in[1];
  const int*   feat_idx = (const int*)d_in[2];
  const float* wlookup  = (const float*)d_in[3];
  const float* plookup  = (const float*)d_in[4];
  const float* Wih1f = (const float*)d_in[5];
  const float* Whh1f = (const float*)d_in[6];
  const float* bih1f = (const float*)d_in[7];
  const float* bhh1f = (const float*)d_in[8];
  const float* Wih1b = (const float*)d_in[9];
  const float* Whh1b = (const float*)d_in[10];
  const float* bih1b = (const float*)d_in[11];
  const float* bhh1b = (const float*)d_in[12];
  const float* Wih2f = (const float*)d_in[13];
  const float* Whh2f = (const float*)d_in[14];
  const float* bih2f = (const float*)d_in[15];
  const float* bhh2f = (const float*)d_in[16];
  const float* Wih2b = (const float*)d_in[17];
  const float* Whh2b = (const float*)d_in[18];
  const float* bih2b = (const float*)d_in[19];
  const float* bhh2b = (const float*)d_in[20];
  const float* hidLayer  = (const float*)d_in[21];
  const float* hidBias   = (const float*)d_in[22];
  const float* outLayer  = (const float*)d_in[23];
  const float* outBias   = (const float*)d_in[24];
  const float* rhidLayer = (const float*)d_in[25];
  const float* rhidBias  = (const float*)d_in[26];
  const float* routLayer = (const float*)d_in[27];
  const float* routBias  = (const float*)d_in[28];

  float* ws = (float*)d_ws;
  // workspace layout (floats)
  const size_t F_IVEC = 0;
  const size_t F_XGF  = F_IVEC + (size_t)kTok * kD1;      //  2,621,440
  const size_t F_XGB  = F_XGF + (size_t)kTok * kG4;       // +16,777,216
  const size_t F_VEC1 = F_XGB + (size_t)kTok * kG4;
  const size_t F_VEC2 = F_VEC1 + (size_t)kTok * kLD;
  const size_t F_WHHT = F_VEC2 + (size_t)kTok * kLD;
  const size_t F_BSUM = F_WHHT + (size_t)4 * kG4 * kH;
  const size_t F_END  = F_BSUM + 4 * kG4;                 // 54,005,760 floats (~206 MB)
  const size_t F_HID  = F_XGF;                            // overlay: hidcat after rec L2
  if (ws_size < F_END * sizeof(float)) return;            // ws too small -> loud failure

  float* ivec  = ws + F_IVEC;
  float* xg_f  = ws + F_XGF;
  float* xg_b  = ws + F_XGB;
  float* vec1  = ws + F_VEC1;
  float* vec2  = ws + F_VEC2;
  float* whhT  = ws + F_WHHT;
  float* bsum  = ws + F_BSUM;
  float* hidc  = ws + F_HID;
  float* outp  = (float*)d_out;

  const int BIG = 1 << 30;

  // 1. bias sums + WhhT transposes + embeddings
  prep_bias<<<16, 256, 0, stream>>>(bih1f, bhh1f, bih1b, bhh1b,
                                    bih2f, bhh2f, bih2b, bhh2b, bsum);
  transpose_whh<<<dim3(8, 32, 4), dim3(32, 8), 0, stream>>>(Whh1f, Whh1b, Whh2f, Whh2b, whhT);
  embed_kernel<<<(kTok * 40 + 255) / 256, 256, 0, stream>>>(word_ids, pos_ids,
                                                            wlookup, plookup, ivec);
  // 2. layer-1 input gates
  gemm_kernel<false, false><<<dim3(8, 128), 256, 0, stream>>>(
      ivec, kD1, Wih1f, Wih1f, BIG, bsum + 0, bsum, nullptr, nullptr,
      xg_f, kG4, kG4, kD1);
  gemm_kernel<false, false><<<dim3(8, 128), 256, 0, stream>>>(
      ivec, kD1, Wih1b, Wih1b, BIG, bsum + 1024, bsum, nullptr, nullptr,
      xg_b, kG4, kG4, kD1);
  // 3. layer-1 recurrence
  lstm_rec_kernel<<<64, 512, 0, stream>>>(xg_f, xg_b, whhT, whhT + 262144, vec1);
  // 4. layer-2 input gates
  gemm_kernel<false, false><<<dim3(8, 128), 256, 0, stream>>>(
      vec1, kLD, Wih2f, Wih2f, BIG, bsum + 2048, bsum, nullptr, nullptr,
      xg_f, kG4, kG4, kLD);
  gemm_kernel<false, false><<<dim3(8, 128), 256, 0, stream>>>(
      vec1, kLD, Wih2b, Wih2b, BIG, bsum + 3072, bsum, nullptr, nullptr,
      xg_b, kG4, kG4, kLD);
  // 5. layer-2 recurrence
  lstm_rec_kernel<<<64, 512, 0, stream>>>(xg_f, xg_b, whhT + 2 * 262144,
                                          whhT + 3 * 262144, vec2);
  // 6. gather + hid/rhid GEMM with tanh (hidLayer rows 0:512, rhidLayer 512:1024)
  gemm_kernel<true, true><<<dim3(8, 128), 256, 0, stream>>>(
      nullptr, 0, hidLayer, rhidLayer, 512, hidBias, rhidBias, vec2, feat_idx,
      hidc, kG4, kG4, kFeat);
  // 7. output heads -> d_out (out [B,T,3] then rout [B,T,93])
  gemm_kernel<false, false><<<dim3(1, 128), 256, 0, stream>>>(
      hidc, kG4, outLayer, outLayer, BIG, outBias, outBias, nullptr, nullptr,
      outp, 3, 3, 512);
  gemm_kernel<false, false><<<dim3(1, 128), 256, 0, stream>>>(
      hidc + 512, kG4, routLayer, routLayer, BIG, routBias, routBias, nullptr, nullptr,
      outp + (size_t)kTok * 3, 93, 93, 512);
}

// Round 3
// 4659.357 us; speedup vs baseline: 2.4789x; 2.4789x over previous
//
#include <hip/hip_runtime.h>
#include <hip/hip_fp16.h>
#include <math.h>

// ---------------------------------------------------------------------------
// ArcHybridLSTM forward on MI355X — round 3: CU-resident fp16 LSTM weights.
// Pipeline:
//   1. embed:       ivec[B,S,160] = cat(wlookup[word], plookup[pos])
//   2. gemm xg1f/1b: xg = ivec @ Wih^T + (bih+bhh)        [B,S,1024]
//   3. lstm_rec L1:  -> vec1[B,S,512]  (f cols 0:256, b cols 256:512)
//   4. gemm xg2f/2b: xg = vec1 @ Wih2^T + bias
//   5. lstm_rec L2:  -> vec2[B,S,512]
//   6. gather-GEMM:  hidcat[B*T,1024] = tanh(feats @ [hidLayer|rhidLayer]^T + b)
//   7. small GEMMs:  out[B,T,3], rout[B,T,93] -> d_out (concatenated)
//
// lstm_rec v3: v1 was per-CU-L2-BW-bound (1MB Whh re-streamed per step at
// ~65 GB/s/CU -> 15.3us/step). v3 makes weights CU-resident as fp16 pairs:
// 512 thr/WG, thread owns gates {2t,2t+1}; 96 pairs/gate in VGPRs (192 regs)
// + 32 pairs/gate in swizzled LDS (128 KB). Dot via v_dot2_f32_f16 (fp32
// accum); h carried fp32, fp16 only inside the recurrent dot. 128 WGs.
// ---------------------------------------------------------------------------

namespace {
constexpr int kB = 64, kS = 256, kH = 256, kG4 = 1024;   // batch, seq, hidden, 4H
constexpr int kD1 = 160, kLD = 512;                      // ivec dim, LSTM concat dim
constexpr int kFeat = 6144, kSlots = 12;
constexpr int kTok = kB * kS;                            // 16384 rows everywhere
}

typedef _Float16 h2 __attribute__((ext_vector_type(2)));

#if __has_builtin(__builtin_amdgcn_fdot2)
#define USE_FDOT2 1
#else
#define USE_FDOT2 0
#endif

__device__ __forceinline__ float dot2acc(h2 w, h2 hh, float acc) {
#if USE_FDOT2
  return __builtin_amdgcn_fdot2(w, hh, acc, false);
#else
  return fmaf((float)w.x, (float)hh.x, fmaf((float)w.y, (float)hh.y, acc));
#endif
}

// ---------------- embeddings ----------------
__global__ void embed_kernel(const int* __restrict__ wid, const int* __restrict__ pid,
                             const float* __restrict__ wl, const float* __restrict__ pl,
                             float* __restrict__ ivec) {
  int tid = blockIdx.x * blockDim.x + threadIdx.x;  // kTok * 40 float4 chunks
  if (tid >= kTok * 40) return;
  int tok = tid / 40;
  int c = tid - tok * 40;
  float4 v;
  if (c < 32) v = ((const float4*)wl)[(size_t)wid[tok] * 32 + c];
  else        v = ((const float4*)pl)[(size_t)pid[tok] * 8 + (c - 32)];
  ((float4*)ivec)[(size_t)tok * 40 + c] = v;
}

// ---------------- bias sums (bih+bhh per layer/dir) ----------------
__global__ void prep_bias(const float* __restrict__ b0, const float* __restrict__ b1,
                          const float* __restrict__ b2, const float* __restrict__ b3,
                          const float* __restrict__ b4, const float* __restrict__ b5,
                          const float* __restrict__ b6, const float* __restrict__ b7,
                          float* __restrict__ bsum) {
  int tid = blockIdx.x * blockDim.x + threadIdx.x;
  if (tid >= 4 * kG4) return;
  int grp = tid >> 10, i = tid & 1023;
  const float* x; const float* y;
  switch (grp) {
    case 0: x = b0; y = b1; break;
    case 1: x = b2; y = b3; break;
    case 2: x = b4; y = b5; break;
    default: x = b6; y = b7; break;
  }
  bsum[tid] = x[i] + y[i];
}

// ---------------- generic fp32 GEMM: C = act(A @ W^T + bias) ----------------
// A: [16384, K] (lda), or gathered feats when GATHER (vsrc=vec2, fidx).
// W rows n<nsplit from W, else W2[n-nsplit]; same for bias. 128x128x8 tile,
// 256 threads, 8x8 per-thread register tile.
template <bool GATHER, bool TANH>
__global__ __launch_bounds__(256) void gemm_kernel(
    const float* __restrict__ A, int lda,
    const float* __restrict__ W, const float* __restrict__ W2, int nsplit,
    const float* __restrict__ bias, const float* __restrict__ bias2,
    const float* __restrict__ vsrc, const int* __restrict__ fidx,
    float* __restrict__ C, int ldc, int N, int K) {
  __shared__ float As[8][128];
  __shared__ float Bs[8][128];
  const int tid = threadIdx.x;
  const int m0 = blockIdx.y * 128;
  const int n0 = blockIdx.x * 128;
  const int tx = tid & 15, ty = tid >> 4;
  const int lm = tid >> 1;           // 0..127 tile row
  const int lk = (tid & 1) * 4;      // 0 or 4
  float acc[8][8] = {};

  for (int k0 = 0; k0 < K; k0 += 8) {
    float4 av;
    if (GATHER) {
      int m = m0 + lm, k = k0 + lk;
      int slot = k >> 9;
      int idx = fidx[m * kSlots + slot];
      int b = m >> 8;
      av = *(const float4*)(vsrc + ((size_t)((b << 8) + idx) << 9) + (k & 511));
    } else {
      av = *(const float4*)(A + (size_t)(m0 + lm) * lda + k0 + lk);
    }
    const int n = n0 + lm;
    float4 bv = make_float4(0.f, 0.f, 0.f, 0.f);
    if (n < N) {
      const float* Wr = (n < nsplit) ? (W + (size_t)n * K)
                                     : (W2 + (size_t)(n - nsplit) * K);
      bv = *(const float4*)(Wr + k0 + lk);
    }
    __syncthreads();
    As[lk + 0][lm] = av.x; As[lk + 1][lm] = av.y;
    As[lk + 2][lm] = av.z; As[lk + 3][lm] = av.w;
    Bs[lk + 0][lm] = bv.x; Bs[lk + 1][lm] = bv.y;
    Bs[lk + 2][lm] = bv.z; Bs[lk + 3][lm] = bv.w;
    __syncthreads();
#pragma unroll
    for (int kk = 0; kk < 8; kk++) {
      float a[8], b8[8];
      *(float4*)&a[0]  = *(const float4*)&As[kk][ty * 8];
      *(float4*)&a[4]  = *(const float4*)&As[kk][ty * 8 + 4];
      *(float4*)&b8[0] = *(const float4*)&Bs[kk][tx * 8];
      *(float4*)&b8[4] = *(const float4*)&Bs[kk][tx * 8 + 4];
#pragma unroll
      for (int i = 0; i < 8; i++)
#pragma unroll
        for (int j = 0; j < 8; j++)
          acc[i][j] = fmaf(a[i], b8[j], acc[i][j]);
    }
  }
#pragma unroll
  for (int i = 0; i < 8; i++) {
    size_t m = m0 + ty * 8 + i;
#pragma unroll
    for (int j = 0; j < 8; j++) {
      int n = n0 + tx * 8 + j;
      if (n < N) {
        float bb = (n < nsplit) ? bias[n] : bias2[n - nsplit];
        float v = acc[i][j] + bb;
        if (TANH) v = tanhf(v);
        C[m * ldc + n] = v;
      }
    }
  }
}

// ---------------- LSTM recurrence v3: CU-resident fp16 weights -------------
// grid 128: dir = bid&1, row = bid>>1. 512 threads; thread t owns gates
// {2t, 2t+1}. Weights as fp16 pairs: j=0..95 in VGPRs (h2 wA/wB[96]),
// j=96..127 in LDS uint4-packed, index swizzled t^((t>>3)&7) so per-lane
// b128 reads spread across all banks (T2). h: fp32 master in out[] + carry;
// fp16-pair copy in hp_lds for the dot (broadcast b128 reads).
// Per step: g = sum_k Whh[g][k]*h[k] + xg  (fp32 accum via v_dot2_f32_f16),
// then 256 lanes do the cell nonlinearity, c_state in register.
__global__ __launch_bounds__(512, 2) void lstm_rec_kernel(
    const float* __restrict__ xg_f, const float* __restrict__ xg_b,
    const float* __restrict__ Whh_f, const float* __restrict__ Whh_b,
    float* __restrict__ out /* [B][S][512] */) {
  __shared__ uint4 wlds4[16 * 512];                 // 128 KB: LDS weight slice
  __shared__ __align__(16) _Float16 hp_lds[kH];     // 512 B: h as fp16 pairs
  __shared__ float g_lds[kG4];                      // 4 KB: gate exchange

  const int bid = blockIdx.x;
  const int dir = bid & 1;
  const int row = bid >> 1;
  const float* xg  = dir ? xg_b : xg_f;
  const float* Whh = dir ? Whh_b : Whh_f;
  const int t = threadIdx.x;                        // owns gates 2t, 2t+1
  const int tsw = t ^ ((t >> 3) & 7);               // bank-spread swizzle

  // ---- one-time: weight rows 2t, 2t+1 -> fp16 pairs in VGPR + LDS ----
  h2 wA[96], wB[96];
  const float2* r0 = (const float2*)(Whh + (size_t)(2 * t) * kH);
  const float2* r1 = (const float2*)(Whh + (size_t)(2 * t + 1) * kH);
#pragma unroll
  for (int j = 0; j < 96; ++j) {
    float2 w0 = r0[j]; wA[j].x = (_Float16)w0.x; wA[j].y = (_Float16)w0.y;
    float2 w1 = r1[j]; wB[j].x = (_Float16)w1.x; wB[j].y = (_Float16)w1.y;
  }
#pragma unroll
  for (int q = 0; q < 8; ++q) {
    unsigned int u0[4], u1[4];
#pragma unroll
    for (int p = 0; p < 4; ++p) {
      float2 f0 = r0[96 + 4 * q + p];
      float2 f1 = r1[96 + 4 * q + p];
      h2 a; a.x = (_Float16)f0.x; a.y = (_Float16)f0.y;
      h2 b; b.x = (_Float16)f1.x; b.y = (_Float16)f1.y;
      u0[p] = __builtin_bit_cast(unsigned int, a);
      u1[p] = __builtin_bit_cast(unsigned int, b);
    }
    wlds4[q * 512 + tsw]       = make_uint4(u0[0], u0[1], u0[2], u0[3]);
    wlds4[(8 + q) * 512 + tsw] = make_uint4(u1[0], u1[1], u1[2], u1[3]);
  }
  if (t < 32) ((uint4*)hp_lds)[t] = make_uint4(0, 0, 0, 0);
  float c_state = 0.f;  // live in threads t < 256
  __syncthreads();

  const uint4* hp4 = (const uint4*)hp_lds;  // 32 entries of 4 fp16-pairs
  const int s0 = dir ? (kS - 1) : 0;
  float2 xv = *(const float2*)(xg + ((size_t)(row * kS + s0)) * kG4 + 2 * t);

  for (int it = 0; it < kS; ++it) {
    const int s = dir ? (kS - 1 - it) : it;
    float a0e = xv.x, a1e = xv.y, a0o = 0.f, a1o = 0.f;
    // prefetch next step's xg (latency hides under the dot)
    float2 xv_next = make_float2(0.f, 0.f);
    if (it + 1 < kS) {
      const int sn = dir ? (kS - 2 - it) : (it + 1);
      xv_next = *(const float2*)(xg + ((size_t)(row * kS + sn)) * kG4 + 2 * t);
    }
    // ---- dot: VGPR-resident pairs j=0..95 ----
#pragma unroll
    for (int j4 = 0; j4 < 24; ++j4) {
      uint4 hv = hp4[j4];
      h2 h0 = __builtin_bit_cast(h2, hv.x);
      h2 h1 = __builtin_bit_cast(h2, hv.y);
      h2 hh2 = __builtin_bit_cast(h2, hv.z);
      h2 h3 = __builtin_bit_cast(h2, hv.w);
      a0e = dot2acc(wA[4 * j4 + 0], h0, a0e);  a1e = dot2acc(wB[4 * j4 + 0], h0, a1e);
      a0o = dot2acc(wA[4 * j4 + 1], h1, a0o);  a1o = dot2acc(wB[4 * j4 + 1], h1, a1o);
      a0e = dot2acc(wA[4 * j4 + 2], hh2, a0e); a1e = dot2acc(wB[4 * j4 + 2], hh2, a1e);
      a0o = dot2acc(wA[4 * j4 + 3], h3, a0o);  a1o = dot2acc(wB[4 * j4 + 3], h3, a1o);
    }
    // ---- dot: LDS-resident pairs j=96..127 ----
#pragma unroll
    for (int q = 0; q < 8; ++q) {
      uint4 hv = hp4[24 + q];
      uint4 w0v = wlds4[q * 512 + tsw];
      uint4 w1v = wlds4[(8 + q) * 512 + tsw];
      h2 h0 = __builtin_bit_cast(h2, hv.x);
      h2 h1 = __builtin_bit_cast(h2, hv.y);
      h2 hh2 = __builtin_bit_cast(h2, hv.z);
      h2 h3 = __builtin_bit_cast(h2, hv.w);
      a0e = dot2acc(__builtin_bit_cast(h2, w0v.x), h0, a0e);
      a1e = dot2acc(__builtin_bit_cast(h2, w1v.x), h0, a1e);
      a0o = dot2acc(__builtin_bit_cast(h2, w0v.y), h1, a0o);
      a1o = dot2acc(__builtin_bit_cast(h2, w1v.y), h1, a1o);
      a0e = dot2acc(__builtin_bit_cast(h2, w0v.z), hh2, a0e);
      a1e = dot2acc(__builtin_bit_cast(h2, w1v.z), hh2, a1e);
      a0o = dot2acc(__builtin_bit_cast(h2, w0v.w), h3, a0o);
      a1o = dot2acc(__builtin_bit_cast(h2, w1v.w), h3, a1o);
    }
    ((float2*)g_lds)[t] = make_float2(a0e + a0o, a1e + a1o);
    __syncthreads();
    // ---- cell nonlinearity (threads t < 256, col = t) ----
    if (t < kH) {
      float gi = g_lds[t];
      float gf = g_lds[t + 256];
      float gg = g_lds[t + 512];
      float go = g_lds[t + 768];
      float i_ = 1.f / (1.f + __expf(-gi));
      float f_ = 1.f / (1.f + __expf(-gf));
      float g_ = tanhf(gg);
      float o_ = 1.f / (1.f + __expf(-go));
      c_state = f_ * c_state + i_ * g_;
      float h = o_ * tanhf(c_state);
      hp_lds[t] = (_Float16)h;
      out[((size_t)(row * kS + s)) * kLD + dir * kH + t] = h;
    }
    __syncthreads();
    xv = xv_next;
  }
}

// ---------------------------------------------------------------------------
extern "C" void kernel_launch(void* const* d_in, const int* in_sizes, int n_in,
                              void* d_out, int out_size, void* d_ws, size_t ws_size,
                              hipStream_t stream) {
  const int*   word_ids = (const int*)d_in[0];
  const int*   pos_ids  = (const int*)d_in[1];
  const int*   feat_idx = (const int*)d_in[2];
  const float* wlookup  = (const float*)d_in[3];
  const float* plookup  = (const float*)d_in[4];
  const float* Wih1f = (const float*)d_in[5];
  const float* Whh1f = (const float*)d_in[6];
  const float* bih1f = (const float*)d_in[7];
  const float* bhh1f = (const float*)d_in[8];
  const float* Wih1b = (const float*)d_in[9];
  const float* Whh1b = (const float*)d_in[10];
  const float* bih1b = (const float*)d_in[11];
  const float* bhh1b = (const float*)d_in[12];
  const float* Wih2f = (const float*)d_in[13];
  const float* Whh2f = (const float*)d_in[14];
  const float* bih2f = (const float*)d_in[15];
  const float* bhh2f = (const float*)d_in[16];
  const float* Wih2b = (const float*)d_in[17];
  const float* Whh2b = (const float*)d_in[18];
  const float* bih2b = (const float*)d_in[19];
  const float* bhh2b = (const float*)d_in[20];
  const float* hidLayer  = (const float*)d_in[21];
  const float* hidBias   = (const float*)d_in[22];
  const float* outLayer  = (const float*)d_in[23];
  const float* outBias   = (const float*)d_in[24];
  const float* rhidLayer = (const float*)d_in[25];
  const float* rhidBias  = (const float*)d_in[26];
  const float* routLayer = (const float*)d_in[27];
  const float* routBias  = (const float*)d_in[28];

  float* ws = (float*)d_ws;
  // workspace layout (floats)
  const size_t F_IVEC = 0;
  const size_t F_XGF  = F_IVEC + (size_t)kTok * kD1;      //  2,621,440
  const size_t F_XGB  = F_XGF + (size_t)kTok * kG4;       // +16,777,216
  const size_t F_VEC1 = F_XGB + (size_t)kTok * kG4;
  const size_t F_VEC2 = F_VEC1 + (size_t)kTok * kLD;
  const size_t F_BSUM = F_VEC2 + (size_t)kTok * kLD;
  const size_t F_END  = F_BSUM + 4 * kG4;                 // ~202 MB
  const size_t F_HID  = F_XGF;                            // overlay: hidcat after rec L2
  if (ws_size < F_END * sizeof(float)) return;            // ws too small -> loud failure

  float* ivec  = ws + F_IVEC;
  float* xg_f  = ws + F_XGF;
  float* xg_b  = ws + F_XGB;
  float* vec1  = ws + F_VEC1;
  float* vec2  = ws + F_VEC2;
  float* bsum  = ws + F_BSUM;
  float* hidc  = ws + F_HID;
  float* outp  = (float*)d_out;

  const int BIG = 1 << 30;

  // 1. bias sums + embeddings
  prep_bias<<<16, 256, 0, stream>>>(bih1f, bhh1f, bih1b, bhh1b,
                                    bih2f, bhh2f, bih2b, bhh2b, bsum);
  embed_kernel<<<(kTok * 40 + 255) / 256, 256, 0, stream>>>(word_ids, pos_ids,
                                                            wlookup, plookup, ivec);
  // 2. layer-1 input gates
  gemm_kernel<false, false><<<dim3(8, 128), 256, 0, stream>>>(
      ivec, kD1, Wih1f, Wih1f, BIG, bsum + 0, bsum, nullptr, nullptr,
      xg_f, kG4, kG4, kD1);
  gemm_kernel<false, false><<<dim3(8, 128), 256, 0, stream>>>(
      ivec, kD1, Wih1b, Wih1b, BIG, bsum + 1024, bsum, nullptr, nullptr,
      xg_b, kG4, kG4, kD1);
  // 3. layer-1 recurrence
  lstm_rec_kernel<<<128, 512, 0, stream>>>(xg_f, xg_b, Whh1f, Whh1b, vec1);
  // 4. layer-2 input gates
  gemm_kernel<false, false><<<dim3(8, 128), 256, 0, stream>>>(
      vec1, kLD, Wih2f, Wih2f, BIG, bsum + 2048, bsum, nullptr, nullptr,
      xg_f, kG4, kG4, kLD);
  gemm_kernel<false, false><<<dim3(8, 128), 256, 0, stream>>>(
      vec1, kLD, Wih2b, Wih2b, BIG, bsum + 3072, bsum, nullptr, nullptr,
      xg_b, kG4, kG4, kLD);
  // 5. layer-2 recurrence
  lstm_rec_kernel<<<128, 512, 0, stream>>>(xg_f, xg_b, Whh2f, Whh2b, vec2);
  // 6. gather + hid/rhid GEMM with tanh (hidLayer rows 0:512, rhidLayer 512:1024)
  gemm_kernel<true, true><<<dim3(8, 128), 256, 0, stream>>>(
      nullptr, 0, hidLayer, rhidLayer, 512, hidBias, rhidBias, vec2, feat_idx,
      hidc, kG4, kG4, kFeat);
  // 7. output heads -> d_out (out [B,T,3] then rout [B,T,93])
  gemm_kernel<false, false><<<dim3(1, 128), 256, 0, stream>>>(
      hidc, kG4, outLayer, outLayer, BIG, outBias, outBias, nullptr, nullptr,
      outp, 3, 3, 512);
  gemm_kernel<false, false><<<dim3(1, 128), 256, 0, stream>>>(
      hidc + 512, kG4, routLayer, routLayer, BIG, routBias, routBias, nullptr, nullptr,
      outp + (size_t)kTok * 3, 93, 93, 512);
}

// Round 4
// 1790.790 us; speedup vs baseline: 6.4496x; 2.6018x over previous
//
#include <hip/hip_runtime.h>
#include <hip/hip_fp16.h>
#include <math.h>

// ---------------------------------------------------------------------------
// ArcHybridLSTM forward on MI355X — round 4: f16 MFMA for all large GEMMs.
//   1. embed_h:      ivec_h[B*S,192] fp16 (160 real + 32 zero-pad)
//   2. mfma_gemm:    xg = ivec_h @ Wih^T + (bih+bhh)   [B*S,1024] fp32, K=192
//   3. lstm_rec L1:  -> vec1h[B*S,512] fp16
//   4. mfma_gemm:    xg2 (K=512)
//   5. lstm_rec L2:  -> vec2h fp16
//   6. mfma_gemm<GATHER,TANH>: hidc[B*S,1024] = tanh(feats@[hid|rhid]^T+b),
//      K=6144, gather fused into per-lane global_load_lds source addresses
//   7. fp32 gemm heads: out[B,T,3], rout[B,T,93] -> d_out
//
// mfma_gemm: 128x128 tile, BK=64, 4 waves (2x2 of 64x64), 16x16x32_f16,
// global_load_lds width-16, T2 xor-swizzle (chunk^=row&7) on BOTH the
// pre-swizzled global source and the ds_read_b128 side (rule #21).
// Round-3 counters: gather-GEMM 2.81ms VALUBusy 72% MfmaUtil 0 (73 TF fp32
// VALU) -> matrix pipe. LSTM rec unchanged (round-5 target).
// ---------------------------------------------------------------------------

namespace {
constexpr int kB = 64, kS = 256, kH = 256, kG4 = 1024;   // batch, seq, hidden, 4H
constexpr int kLD = 512;                                 // LSTM concat dim
constexpr int kTok = kB * kS;                            // 16384 rows everywhere
}

typedef _Float16 h2 __attribute__((ext_vector_type(2)));
typedef _Float16 h4 __attribute__((ext_vector_type(4)));
typedef _Float16 h8 __attribute__((ext_vector_type(8)));
typedef float f4 __attribute__((ext_vector_type(4)));

#if __has_builtin(__builtin_amdgcn_fdot2)
#define USE_FDOT2 1
#else
#define USE_FDOT2 0
#endif

__device__ __forceinline__ float dot2acc(h2 w, h2 hh, float acc) {
#if USE_FDOT2
  return __builtin_amdgcn_fdot2(w, hh, acc, false);
#else
  return fmaf((float)w.x, (float)hh.x, fmaf((float)w.y, (float)hh.y, acc));
#endif
}

// 16B global->LDS stage. lds_base must be wave-uniform; lane writes base+l*16.
__device__ __forceinline__ void stage16(const void* g, void* lds_base, int lane) {
#if __has_builtin(__builtin_amdgcn_global_load_lds)
  (void)lane;
  __builtin_amdgcn_global_load_lds((const __attribute__((address_space(1))) void*)g,
                                   (__attribute__((address_space(3))) void*)lds_base,
                                   16, 0, 0);
#else
  *(uint4*)((char*)lds_base + lane * 16) = *(const uint4*)g;
#endif
}

// ---------------- embeddings -> fp16, K padded 160->192 ----------------
__global__ void embed_h(const int* __restrict__ wid, const int* __restrict__ pid,
                        const float* __restrict__ wl, const float* __restrict__ pl,
                        _Float16* __restrict__ dst) {
  int tid = blockIdx.x * blockDim.x + threadIdx.x;  // kTok * 24 chunks of 8 cols
  if (tid >= kTok * 24) return;
  int tok = tid / 24, c8 = tid % 24;
  h8 o;
  if (c8 < 20) {
    const float* src = (c8 < 16) ? (wl + (size_t)wid[tok] * 128 + c8 * 8)
                                 : (pl + (size_t)pid[tok] * 32 + (c8 - 16) * 8);
    float4 v0 = *(const float4*)src;
    float4 v1 = *(const float4*)(src + 4);
    o[0] = (_Float16)v0.x; o[1] = (_Float16)v0.y;
    o[2] = (_Float16)v0.z; o[3] = (_Float16)v0.w;
    o[4] = (_Float16)v1.x; o[5] = (_Float16)v1.y;
    o[6] = (_Float16)v1.z; o[7] = (_Float16)v1.w;
  } else {
    o = (h8)(_Float16)0.f;
  }
  *(h8*)(dst + (size_t)tok * 192 + c8 * 8) = o;
}

// ---------------- fp32 -> fp16 with K zero-pad ----------------
__global__ void f2h_pad(const float* __restrict__ src, _Float16* __restrict__ dst,
                        int rows, int Kin, int Kpad) {
  int per = Kpad >> 2;
  int tid = blockIdx.x * blockDim.x + threadIdx.x;
  if (tid >= rows * per) return;
  int row = tid / per, c4 = (tid % per) << 2;
  h4 o;
  if (c4 < Kin) {
    float4 v = *(const float4*)(src + (size_t)row * Kin + c4);
    o[0] = (_Float16)v.x; o[1] = (_Float16)v.y;
    o[2] = (_Float16)v.z; o[3] = (_Float16)v.w;
  } else {
    o = (h4)(_Float16)0.f;
  }
  *(h4*)(dst + (size_t)row * Kpad + c4) = o;
}

// ---------------- bias sums (bih+bhh per layer/dir) ----------------
__global__ void prep_bias(const float* __restrict__ b0, const float* __restrict__ b1,
                          const float* __restrict__ b2, const float* __restrict__ b3,
                          const float* __restrict__ b4, const float* __restrict__ b5,
                          const float* __restrict__ b6, const float* __restrict__ b7,
                          float* __restrict__ bsum) {
  int tid = blockIdx.x * blockDim.x + threadIdx.x;
  if (tid >= 4 * kG4) return;
  int grp = tid >> 10, i = tid & 1023;
  const float* x; const float* y;
  switch (grp) {
    case 0: x = b0; y = b1; break;
    case 1: x = b2; y = b3; break;
    case 2: x = b4; y = b5; break;
    default: x = b6; y = b7; break;
  }
  bsum[tid] = x[i] + y[i];
}

__global__ void concat_bias(const float* __restrict__ a, const float* __restrict__ b,
                            float* __restrict__ dst) {
  int tid = blockIdx.x * blockDim.x + threadIdx.x;
  if (tid >= kG4) return;
  dst[tid] = (tid < 512) ? a[tid] : b[tid - 512];
}

// ---------------- f16 MFMA GEMM: C[16384,1024] = act(A @ W^T + bias) -------
// A fp16 [16384][lda] (or gathered from vsrc[B*S][512] via fidx when GATHER).
// W fp16 [1024][K]. C fp32 ldc=1024. K % 64 == 0. 128x128 tile, BK=64,
// 4 waves 2x2, per-wave 4x4 16x16 frags. LDS tiles [128][64] fp16 with 16B
// chunk position p = c ^ (row&7): staged via pre-swizzled per-lane global
// source (linear LDS dest), read back with the same xor -> even 8/bank.
template <bool GATHER, bool TANH>
__global__ __launch_bounds__(256) void mfma_gemm(
    const _Float16* __restrict__ A, int lda,
    const _Float16* __restrict__ W,
    const float* __restrict__ bias,
    const _Float16* __restrict__ vsrc, const int* __restrict__ fidx,
    float* __restrict__ C, int K) {
  __shared__ _Float16 Asm[128 * 64];  // 16 KB
  __shared__ _Float16 Bsm[128 * 64];  // 16 KB
  const int tid = threadIdx.x;
  const int w = tid >> 6, l = tid & 63;
  const int wr = w >> 1, wc = w & 1;
  const int m0 = blockIdx.y * 128, n0 = blockIdx.x * 128;
  const int lrow = l & 15, lk8 = (l >> 4) << 3;
  const int stg_r = l >> 3;        // row-within-8 for staging
  const int stg_c = (l & 7) ^ stg_r;  // source chunk for this lane's LDS slot

  f4 acc[4][4] = {};

  for (int k0 = 0; k0 < K; k0 += 64) {
#pragma unroll
    for (int ii = 0; ii < 4; ++ii) {
      const int r = w * 32 + ii * 8 + stg_r;   // tile row (A: m, B: n)
      const _Float16* ga;
      if (GATHER) {
        const int token = m0 + r;
        const int slot = k0 >> 9;              // 64 | 512: never crosses a slot
        const int idx = fidx[token * 12 + slot];
        ga = vsrc + ((((size_t)(token >> 8) << 8) + idx) << 9) + (k0 & 511) + (stg_c << 3);
      } else {
        ga = A + (size_t)(m0 + r) * lda + k0 + (stg_c << 3);
      }
      stage16(ga, &Asm[(size_t)(w * 32 + ii * 8) * 64], l);
      const _Float16* gb = W + (size_t)(n0 + r) * K + k0 + (stg_c << 3);
      stage16(gb, &Bsm[(size_t)(w * 32 + ii * 8) * 64], l);
    }
    __syncthreads();
#pragma unroll
    for (int kk = 0; kk < 64; kk += 32) {
      const int c0 = (kk + lk8) >> 3;
      h8 af[4], bf[4];
#pragma unroll
      for (int m = 0; m < 4; ++m) {
        const int row = wr * 64 + m * 16 + lrow;
        af[m] = *(const h8*)&Asm[row * 64 + ((c0 ^ (row & 7)) << 3)];
      }
#pragma unroll
      for (int n = 0; n < 4; ++n) {
        const int row = wc * 64 + n * 16 + lrow;
        bf[n] = *(const h8*)&Bsm[row * 64 + ((c0 ^ (row & 7)) << 3)];
      }
#pragma unroll
      for (int m = 0; m < 4; ++m)
#pragma unroll
        for (int n = 0; n < 4; ++n)
          acc[m][n] = __builtin_amdgcn_mfma_f32_16x16x32_f16(af[m], bf[n], acc[m][n], 0, 0, 0);
    }
    __syncthreads();
  }
  // epilogue: C/D layout col=lane&15, row=(lane>>4)*4+reg (m89/m91)
#pragma unroll
  for (int n = 0; n < 4; ++n) {
    const int col = n0 + wc * 64 + n * 16 + lrow;
    const float bb = bias[col];
#pragma unroll
    for (int m = 0; m < 4; ++m) {
      const int rowb = m0 + wr * 64 + m * 16 + ((l >> 4) << 2);
#pragma unroll
      for (int r = 0; r < 4; ++r) {
        float v = acc[m][n][r] + bb;
        if (TANH) v = tanhf(v);
        C[(size_t)(rowb + r) * kG4 + col] = v;
      }
    }
  }
}

// ---------------- fp32 GEMM (heads only now) ----------------
template <bool TANH>
__global__ __launch_bounds__(256) void gemm_kernel(
    const float* __restrict__ A, int lda,
    const float* __restrict__ W,
    const float* __restrict__ bias,
    float* __restrict__ C, int ldc, int N, int K) {
  __shared__ float As[8][128];
  __shared__ float Bs[8][128];
  const int tid = threadIdx.x;
  const int m0 = blockIdx.y * 128;
  const int n0 = blockIdx.x * 128;
  const int tx = tid & 15, ty = tid >> 4;
  const int lm = tid >> 1;
  const int lk = (tid & 1) * 4;
  float acc[8][8] = {};

  for (int k0 = 0; k0 < K; k0 += 8) {
    float4 av = *(const float4*)(A + (size_t)(m0 + lm) * lda + k0 + lk);
    const int n = n0 + lm;
    float4 bv = make_float4(0.f, 0.f, 0.f, 0.f);
    if (n < N) bv = *(const float4*)(W + (size_t)n * K + k0 + lk);
    __syncthreads();
    As[lk + 0][lm] = av.x; As[lk + 1][lm] = av.y;
    As[lk + 2][lm] = av.z; As[lk + 3][lm] = av.w;
    Bs[lk + 0][lm] = bv.x; Bs[lk + 1][lm] = bv.y;
    Bs[lk + 2][lm] = bv.z; Bs[lk + 3][lm] = bv.w;
    __syncthreads();
#pragma unroll
    for (int kk = 0; kk < 8; kk++) {
      float a[8], b8[8];
      *(float4*)&a[0]  = *(const float4*)&As[kk][ty * 8];
      *(float4*)&a[4]  = *(const float4*)&As[kk][ty * 8 + 4];
      *(float4*)&b8[0] = *(const float4*)&Bs[kk][tx * 8];
      *(float4*)&b8[4] = *(const float4*)&Bs[kk][tx * 8 + 4];
#pragma unroll
      for (int i = 0; i < 8; i++)
#pragma unroll
        for (int j = 0; j < 8; j++)
          acc[i][j] = fmaf(a[i], b8[j], acc[i][j]);
    }
  }
#pragma unroll
  for (int i = 0; i < 8; i++) {
    size_t m = m0 + ty * 8 + i;
#pragma unroll
    for (int j = 0; j < 8; j++) {
      int n = n0 + tx * 8 + j;
      if (n < N) {
        float v = acc[i][j] + bias[n];
        if (TANH) v = tanhf(v);
        C[m * ldc + n] = v;
      }
    }
  }
}

// ---------------- LSTM recurrence: CU-resident fp16 weights ----------------
// (round-3 structure; output now fp16 directly — consumers are fp16 GEMMs)
__global__ __launch_bounds__(512, 2) void lstm_rec_kernel(
    const float* __restrict__ xg_f, const float* __restrict__ xg_b,
    const float* __restrict__ Whh_f, const float* __restrict__ Whh_b,
    _Float16* __restrict__ out /* [B][S][512] fp16 */) {
  __shared__ uint4 wlds4[16 * 512];                 // 128 KB: LDS weight slice
  __shared__ __align__(16) _Float16 hp_lds[kH];     // h as fp16
  __shared__ float g_lds[kG4];                      // gate exchange

  const int bid = blockIdx.x;
  const int dir = bid & 1;
  const int row = bid >> 1;
  const float* xg  = dir ? xg_b : xg_f;
  const float* Whh = dir ? Whh_b : Whh_f;
  const int t = threadIdx.x;                        // owns gates 2t, 2t+1
  const int tsw = t ^ ((t >> 3) & 7);               // bank-spread swizzle

  h2 wA[96], wB[96];
  const float2* r0 = (const float2*)(Whh + (size_t)(2 * t) * kH);
  const float2* r1 = (const float2*)(Whh + (size_t)(2 * t + 1) * kH);
#pragma unroll
  for (int j = 0; j < 96; ++j) {
    float2 w0 = r0[j]; wA[j].x = (_Float16)w0.x; wA[j].y = (_Float16)w0.y;
    float2 w1 = r1[j]; wB[j].x = (_Float16)w1.x; wB[j].y = (_Float16)w1.y;
  }
#pragma unroll
  for (int q = 0; q < 8; ++q) {
    unsigned int u0[4], u1[4];
#pragma unroll
    for (int p = 0; p < 4; ++p) {
      float2 f0 = r0[96 + 4 * q + p];
      float2 f1 = r1[96 + 4 * q + p];
      h2 a; a.x = (_Float16)f0.x; a.y = (_Float16)f0.y;
      h2 b; b.x = (_Float16)f1.x; b.y = (_Float16)f1.y;
      u0[p] = __builtin_bit_cast(unsigned int, a);
      u1[p] = __builtin_bit_cast(unsigned int, b);
    }
    wlds4[q * 512 + tsw]       = make_uint4(u0[0], u0[1], u0[2], u0[3]);
    wlds4[(8 + q) * 512 + tsw] = make_uint4(u1[0], u1[1], u1[2], u1[3]);
  }
  if (t < 32) ((uint4*)hp_lds)[t] = make_uint4(0, 0, 0, 0);
  float c_state = 0.f;
  __syncthreads();

  const uint4* hp4 = (const uint4*)hp_lds;
  const int s0 = dir ? (kS - 1) : 0;
  float2 xv = *(const float2*)(xg + ((size_t)(row * kS + s0)) * kG4 + 2 * t);

  for (int it = 0; it < kS; ++it) {
    const int s = dir ? (kS - 1 - it) : it;
    float a0e = xv.x, a1e = xv.y, a0o = 0.f, a1o = 0.f;
    float2 xv_next = make_float2(0.f, 0.f);
    if (it + 1 < kS) {
      const int sn = dir ? (kS - 2 - it) : (it + 1);
      xv_next = *(const float2*)(xg + ((size_t)(row * kS + sn)) * kG4 + 2 * t);
    }
#pragma unroll
    for (int j4 = 0; j4 < 24; ++j4) {
      uint4 hv = hp4[j4];
      h2 h0 = __builtin_bit_cast(h2, hv.x);
      h2 h1 = __builtin_bit_cast(h2, hv.y);
      h2 hh2 = __builtin_bit_cast(h2, hv.z);
      h2 h3 = __builtin_bit_cast(h2, hv.w);
      a0e = dot2acc(wA[4 * j4 + 0], h0, a0e);  a1e = dot2acc(wB[4 * j4 + 0], h0, a1e);
      a0o = dot2acc(wA[4 * j4 + 1], h1, a0o);  a1o = dot2acc(wB[4 * j4 + 1], h1, a1o);
      a0e = dot2acc(wA[4 * j4 + 2], hh2, a0e); a1e = dot2acc(wB[4 * j4 + 2], hh2, a1e);
      a0o = dot2acc(wA[4 * j4 + 3], h3, a0o);  a1o = dot2acc(wB[4 * j4 + 3], h3, a1o);
    }
#pragma unroll
    for (int q = 0; q < 8; ++q) {
      uint4 hv = hp4[24 + q];
      uint4 w0v = wlds4[q * 512 + tsw];
      uint4 w1v = wlds4[(8 + q) * 512 + tsw];
      h2 h0 = __builtin_bit_cast(h2, hv.x);
      h2 h1 = __builtin_bit_cast(h2, hv.y);
      h2 hh2 = __builtin_bit_cast(h2, hv.z);
      h2 h3 = __builtin_bit_cast(h2, hv.w);
      a0e = dot2acc(__builtin_bit_cast(h2, w0v.x), h0, a0e);
      a1e = dot2acc(__builtin_bit_cast(h2, w1v.x), h0, a1e);
      a0o = dot2acc(__builtin_bit_cast(h2, w0v.y), h1, a0o);
      a1o = dot2acc(__builtin_bit_cast(h2, w1v.y), h1, a1o);
      a0e = dot2acc(__builtin_bit_cast(h2, w0v.z), hh2, a0e);
      a1e = dot2acc(__builtin_bit_cast(h2, w1v.z), hh2, a1e);
      a0o = dot2acc(__builtin_bit_cast(h2, w0v.w), h3, a0o);
      a1o = dot2acc(__builtin_bit_cast(h2, w1v.w), h3, a1o);
    }
    ((float2*)g_lds)[t] = make_float2(a0e + a0o, a1e + a1o);
    __syncthreads();
    if (t < kH) {
      float gi = g_lds[t];
      float gf = g_lds[t + 256];
      float gg = g_lds[t + 512];
      float go = g_lds[t + 768];
      float i_ = 1.f / (1.f + __expf(-gi));
      float f_ = 1.f / (1.f + __expf(-gf));
      float g_ = tanhf(gg);
      float o_ = 1.f / (1.f + __expf(-go));
      c_state = f_ * c_state + i_ * g_;
      float h = o_ * tanhf(c_state);
      hp_lds[t] = (_Float16)h;
      out[((size_t)(row * kS + s)) * kLD + dir * kH + t] = (_Float16)h;
    }
    __syncthreads();
    xv = xv_next;
  }
}

// ---------------------------------------------------------------------------
extern "C" void kernel_launch(void* const* d_in, const int* in_sizes, int n_in,
                              void* d_out, int out_size, void* d_ws, size_t ws_size,
                              hipStream_t stream) {
  const int*   word_ids = (const int*)d_in[0];
  const int*   pos_ids  = (const int*)d_in[1];
  const int*   feat_idx = (const int*)d_in[2];
  const float* wlookup  = (const float*)d_in[3];
  const float* plookup  = (const float*)d_in[4];
  const float* Wih1f = (const float*)d_in[5];
  const float* Whh1f = (const float*)d_in[6];
  const float* bih1f = (const float*)d_in[7];
  const float* bhh1f = (const float*)d_in[8];
  const float* Wih1b = (const float*)d_in[9];
  const float* Whh1b = (const float*)d_in[10];
  const float* bih1b = (const float*)d_in[11];
  const float* bhh1b = (const float*)d_in[12];
  const float* Wih2f = (const float*)d_in[13];
  const float* Whh2f = (const float*)d_in[14];
  const float* bih2f = (const float*)d_in[15];
  const float* bhh2f = (const float*)d_in[16];
  const float* Wih2b = (const float*)d_in[17];
  const float* Whh2b = (const float*)d_in[18];
  const float* bih2b = (const float*)d_in[19];
  const float* bhh2b = (const float*)d_in[20];
  const float* hidLayer  = (const float*)d_in[21];
  const float* hidBias   = (const float*)d_in[22];
  const float* outLayer  = (const float*)d_in[23];
  const float* outBias   = (const float*)d_in[24];
  const float* rhidLayer = (const float*)d_in[25];
  const float* rhidBias  = (const float*)d_in[26];
  const float* routLayer = (const float*)d_in[27];
  const float* routBias  = (const float*)d_in[28];

  float* ws = (float*)d_ws;
  // workspace layout (float units; fp16 buffers counted as half-floats)
  const size_t F_IVECH = 0;                                  // 16384*192 h = 1.57M f
  const size_t F_XGF   = F_IVECH + (size_t)kTok * 192 / 2;
  const size_t F_XGB   = F_XGF + (size_t)kTok * kG4;         // fp32
  const size_t F_V1H   = F_XGB + (size_t)kTok * kG4;         // 16384*512 h
  const size_t F_V2H   = F_V1H + (size_t)kTok * kLD / 2;
  const size_t F_WHA   = F_V2H + (size_t)kTok * kLD / 2;     // 2*1024*192 h
  const size_t F_WHB   = F_WHA + (size_t)2 * kG4 * 192 / 2;  // 2*1024*512 h
  const size_t F_WHID  = F_WHB + (size_t)2 * kG4 * 512 / 2;  // 1024*6144 h
  const size_t F_BSUM  = F_WHID + (size_t)kG4 * 6144 / 2;
  const size_t F_HB    = F_BSUM + 4 * kG4;
  const size_t F_END   = F_HB + kG4;                         // ~47.4M floats (~190MB)
  const size_t F_HID   = F_XGF;                              // overlay after rec L2
  if (ws_size < F_END * sizeof(float)) return;

  _Float16* ivec_h = (_Float16*)(ws + F_IVECH);
  float*    xg_f   = ws + F_XGF;
  float*    xg_b   = ws + F_XGB;
  _Float16* vec1h  = (_Float16*)(ws + F_V1H);
  _Float16* vec2h  = (_Float16*)(ws + F_V2H);
  _Float16* whA    = (_Float16*)(ws + F_WHA);   // Wih1f | Wih1b, [1024][192] each
  _Float16* whB    = (_Float16*)(ws + F_WHB);   // Wih2f | Wih2b, [1024][512] each
  _Float16* whid   = (_Float16*)(ws + F_WHID);  // hid rows 0:512 | rhid 512:1024
  float*    bsum   = ws + F_BSUM;
  float*    hb     = ws + F_HB;
  float*    hidc   = ws + F_HID;
  float*    outp   = (float*)d_out;

  // 1. weight/bias prep + embeddings
  prep_bias<<<16, 256, 0, stream>>>(bih1f, bhh1f, bih1b, bhh1b,
                                    bih2f, bhh2f, bih2b, bhh2b, bsum);
  concat_bias<<<4, 256, 0, stream>>>(hidBias, rhidBias, hb);
  f2h_pad<<<(1024 * 48 + 255) / 256, 256, 0, stream>>>(Wih1f, whA, 1024, 160, 192);
  f2h_pad<<<(1024 * 48 + 255) / 256, 256, 0, stream>>>(Wih1b, whA + 1024 * 192, 1024, 160, 192);
  f2h_pad<<<(1024 * 128 + 255) / 256, 256, 0, stream>>>(Wih2f, whB, 1024, 512, 512);
  f2h_pad<<<(1024 * 128 + 255) / 256, 256, 0, stream>>>(Wih2b, whB + 1024 * 512, 1024, 512, 512);
  f2h_pad<<<(512 * 1536 + 255) / 256, 256, 0, stream>>>(hidLayer, whid, 512, 6144, 6144);
  f2h_pad<<<(512 * 1536 + 255) / 256, 256, 0, stream>>>(rhidLayer, whid + (size_t)512 * 6144,
                                                        512, 6144, 6144);
  embed_h<<<(kTok * 24 + 255) / 256, 256, 0, stream>>>(word_ids, pos_ids,
                                                       wlookup, plookup, ivec_h);
  // 2. layer-1 input gates (K=192, zero-padded)
  mfma_gemm<false, false><<<dim3(8, 128), 256, 0, stream>>>(
      ivec_h, 192, whA, bsum + 0, nullptr, nullptr, xg_f, 192);
  mfma_gemm<false, false><<<dim3(8, 128), 256, 0, stream>>>(
      ivec_h, 192, whA + 1024 * 192, bsum + 1024, nullptr, nullptr, xg_b, 192);
  // 3. layer-1 recurrence -> fp16
  lstm_rec_kernel<<<128, 512, 0, stream>>>(xg_f, xg_b, Whh1f, Whh1b, vec1h);
  // 4. layer-2 input gates (K=512)
  mfma_gemm<false, false><<<dim3(8, 128), 256, 0, stream>>>(
      vec1h, 512, whB, bsum + 2048, nullptr, nullptr, xg_f, 512);
  mfma_gemm<false, false><<<dim3(8, 128), 256, 0, stream>>>(
      vec1h, 512, whB + 1024 * 512, bsum + 3072, nullptr, nullptr, xg_b, 512);
  // 5. layer-2 recurrence -> fp16
  lstm_rec_kernel<<<128, 512, 0, stream>>>(xg_f, xg_b, Whh2f, Whh2b, vec2h);
  // 6. gather + hid/rhid MFMA GEMM with tanh (K=6144)
  mfma_gemm<true, true><<<dim3(8, 128), 256, 0, stream>>>(
      nullptr, 0, whid, hb, vec2h, feat_idx, hidc, 6144);
  // 7. output heads (fp32) -> d_out: out [B,T,3] then rout [B,T,93]
  gemm_kernel<false><<<dim3(1, 128), 256, 0, stream>>>(
      hidc, kG4, outLayer, outBias, outp, 3, 3, 512);
  gemm_kernel<false><<<dim3(1, 128), 256, 0, stream>>>(
      hidc + 512, kG4, routLayer, routBias, outp + (size_t)kTok * 3, 93, 93, 512);
}

// Round 5
// 1663.142 us; speedup vs baseline: 6.9446x; 1.0768x over previous
//
#include <hip/hip_runtime.h>
#include <hip/hip_fp16.h>
#include <math.h>

// ---------------------------------------------------------------------------
// ArcHybridLSTM forward on MI355X — round 5: restructured LSTM recurrence.
//   1. embed_h:      ivec_h[B*S,192] fp16 (160 real + 32 zero-pad)
//   2. mfma_gemm:    xg = ivec_h @ Wih^T + (bih+bhh)   [B*S,1024] fp32, K=192
//   3. lstm_rec L1:  -> vec1h[B*S,512] fp16
//   4. mfma_gemm:    xg2 (K=512)
//   5. lstm_rec L2:  -> vec2h fp16
//   6. mfma_gemm<GATHER,TANH>: hidc = tanh(feats@[hid|rhid]^T+b), K=6144
//   7. fp32 gemm heads: out[B,T,3], rout[B,T,93] -> d_out
//
// lstm_rec v4 (from round-4 counters: 546us/dispatch, VALUBusy 27%, step
// 2.13us vs ~1380cyc VALU — LDS pipe + 2-barrier + libm-tanh bound):
//   thread pair (t, t^1) owns column c=t>>1: thread handles ALL 4 gates of c
//   over its k-half (kh=t&1). Partial gates combined via shfl_xor(1) (same
//   wave) -> no g_lds, ONE barrier/step. Nonlin redundant in both lanes,
//   exp-based tanh/sigmoid. h double-buffered fp16 in LDS (race-free with
//   single barrier). Weights: 4x48 h2 pairs in VGPR + 4x16 pairs in LDS
//   (128 KB slice, 16 b128 reads/step — capacity-pinned).
// ---------------------------------------------------------------------------

namespace {
constexpr int kB = 64, kS = 256, kH = 256, kG4 = 1024;   // batch, seq, hidden, 4H
constexpr int kLD = 512;                                 // LSTM concat dim
constexpr int kTok = kB * kS;                            // 16384 rows everywhere
}

typedef _Float16 h2 __attribute__((ext_vector_type(2)));
typedef _Float16 h4 __attribute__((ext_vector_type(4)));
typedef _Float16 h8 __attribute__((ext_vector_type(8)));
typedef float f4 __attribute__((ext_vector_type(4)));

#if __has_builtin(__builtin_amdgcn_fdot2)
#define USE_FDOT2 1
#else
#define USE_FDOT2 0
#endif

__device__ __forceinline__ float dot2acc(h2 w, h2 hh, float acc) {
#if USE_FDOT2
  return __builtin_amdgcn_fdot2(w, hh, acc, false);
#else
  return fmaf((float)w.x, (float)hh.x, fmaf((float)w.y, (float)hh.y, acc));
#endif
}

__device__ __forceinline__ float fastrcp(float x) {
#if __has_builtin(__builtin_amdgcn_rcpf)
  return __builtin_amdgcn_rcpf(x);
#else
  return 1.f / x;
#endif
}
// sigmoid: x->-inf: exp(+inf)=inf, rcp(inf)=0 OK; x->+inf: rcp(1)=1 OK.
__device__ __forceinline__ float sigf(float x) { return fastrcp(1.f + __expf(-x)); }
// tanh = 1 - 2/(e^{2x}+1): u=inf -> 1; u=0 -> -1; no NaN paths.
__device__ __forceinline__ float tanhfast(float x) {
  float u = __expf(2.f * x);
  return 1.f - 2.f * fastrcp(u + 1.f);
}

// 16B global->LDS stage. lds_base must be wave-uniform; lane writes base+l*16.
__device__ __forceinline__ void stage16(const void* g, void* lds_base, int lane) {
#if __has_builtin(__builtin_amdgcn_global_load_lds)
  (void)lane;
  __builtin_amdgcn_global_load_lds((const __attribute__((address_space(1))) void*)g,
                                   (__attribute__((address_space(3))) void*)lds_base,
                                   16, 0, 0);
#else
  *(uint4*)((char*)lds_base + lane * 16) = *(const uint4*)g;
#endif
}

// ---------------- embeddings -> fp16, K padded 160->192 ----------------
__global__ void embed_h(const int* __restrict__ wid, const int* __restrict__ pid,
                        const float* __restrict__ wl, const float* __restrict__ pl,
                        _Float16* __restrict__ dst) {
  int tid = blockIdx.x * blockDim.x + threadIdx.x;  // kTok * 24 chunks of 8 cols
  if (tid >= kTok * 24) return;
  int tok = tid / 24, c8 = tid % 24;
  h8 o;
  if (c8 < 20) {
    const float* src = (c8 < 16) ? (wl + (size_t)wid[tok] * 128 + c8 * 8)
                                 : (pl + (size_t)pid[tok] * 32 + (c8 - 16) * 8);
    float4 v0 = *(const float4*)src;
    float4 v1 = *(const float4*)(src + 4);
    o[0] = (_Float16)v0.x; o[1] = (_Float16)v0.y;
    o[2] = (_Float16)v0.z; o[3] = (_Float16)v0.w;
    o[4] = (_Float16)v1.x; o[5] = (_Float16)v1.y;
    o[6] = (_Float16)v1.z; o[7] = (_Float16)v1.w;
  } else {
    o = (h8)(_Float16)0.f;
  }
  *(h8*)(dst + (size_t)tok * 192 + c8 * 8) = o;
}

// ---------------- fp32 -> fp16 with K zero-pad ----------------
__global__ void f2h_pad(const float* __restrict__ src, _Float16* __restrict__ dst,
                        int rows, int Kin, int Kpad) {
  int per = Kpad >> 2;
  int tid = blockIdx.x * blockDim.x + threadIdx.x;
  if (tid >= rows * per) return;
  int row = tid / per, c4 = (tid % per) << 2;
  h4 o;
  if (c4 < Kin) {
    float4 v = *(const float4*)(src + (size_t)row * Kin + c4);
    o[0] = (_Float16)v.x; o[1] = (_Float16)v.y;
    o[2] = (_Float16)v.z; o[3] = (_Float16)v.w;
  } else {
    o = (h4)(_Float16)0.f;
  }
  *(h4*)(dst + (size_t)row * Kpad + c4) = o;
}

// ---------------- bias sums (bih+bhh per layer/dir) ----------------
__global__ void prep_bias(const float* __restrict__ b0, const float* __restrict__ b1,
                          const float* __restrict__ b2, const float* __restrict__ b3,
                          const float* __restrict__ b4, const float* __restrict__ b5,
                          const float* __restrict__ b6, const float* __restrict__ b7,
                          float* __restrict__ bsum) {
  int tid = blockIdx.x * blockDim.x + threadIdx.x;
  if (tid >= 4 * kG4) return;
  int grp = tid >> 10, i = tid & 1023;
  const float* x; const float* y;
  switch (grp) {
    case 0: x = b0; y = b1; break;
    case 1: x = b2; y = b3; break;
    case 2: x = b4; y = b5; break;
    default: x = b6; y = b7; break;
  }
  bsum[tid] = x[i] + y[i];
}

__global__ void concat_bias(const float* __restrict__ a, const float* __restrict__ b,
                            float* __restrict__ dst) {
  int tid = blockIdx.x * blockDim.x + threadIdx.x;
  if (tid >= kG4) return;
  dst[tid] = (tid < 512) ? a[tid] : b[tid - 512];
}

// ---------------- f16 MFMA GEMM: C[16384,1024] = act(A @ W^T + bias) -------
// (unchanged from round 4 — control)
template <bool GATHER, bool TANH>
__global__ __launch_bounds__(256) void mfma_gemm(
    const _Float16* __restrict__ A, int lda,
    const _Float16* __restrict__ W,
    const float* __restrict__ bias,
    const _Float16* __restrict__ vsrc, const int* __restrict__ fidx,
    float* __restrict__ C, int K) {
  __shared__ _Float16 Asm[128 * 64];  // 16 KB
  __shared__ _Float16 Bsm[128 * 64];  // 16 KB
  const int tid = threadIdx.x;
  const int w = tid >> 6, l = tid & 63;
  const int wr = w >> 1, wc = w & 1;
  const int m0 = blockIdx.y * 128, n0 = blockIdx.x * 128;
  const int lrow = l & 15, lk8 = (l >> 4) << 3;
  const int stg_r = l >> 3;
  const int stg_c = (l & 7) ^ stg_r;

  f4 acc[4][4] = {};

  for (int k0 = 0; k0 < K; k0 += 64) {
#pragma unroll
    for (int ii = 0; ii < 4; ++ii) {
      const int r = w * 32 + ii * 8 + stg_r;
      const _Float16* ga;
      if (GATHER) {
        const int token = m0 + r;
        const int slot = k0 >> 9;
        const int idx = fidx[token * 12 + slot];
        ga = vsrc + ((((size_t)(token >> 8) << 8) + idx) << 9) + (k0 & 511) + (stg_c << 3);
      } else {
        ga = A + (size_t)(m0 + r) * lda + k0 + (stg_c << 3);
      }
      stage16(ga, &Asm[(size_t)(w * 32 + ii * 8) * 64], l);
      const _Float16* gb = W + (size_t)(n0 + r) * K + k0 + (stg_c << 3);
      stage16(gb, &Bsm[(size_t)(w * 32 + ii * 8) * 64], l);
    }
    __syncthreads();
#pragma unroll
    for (int kk = 0; kk < 64; kk += 32) {
      const int c0 = (kk + lk8) >> 3;
      h8 af[4], bf[4];
#pragma unroll
      for (int m = 0; m < 4; ++m) {
        const int row = wr * 64 + m * 16 + lrow;
        af[m] = *(const h8*)&Asm[row * 64 + ((c0 ^ (row & 7)) << 3)];
      }
#pragma unroll
      for (int n = 0; n < 4; ++n) {
        const int row = wc * 64 + n * 16 + lrow;
        bf[n] = *(const h8*)&Bsm[row * 64 + ((c0 ^ (row & 7)) << 3)];
      }
#pragma unroll
      for (int m = 0; m < 4; ++m)
#pragma unroll
        for (int n = 0; n < 4; ++n)
          acc[m][n] = __builtin_amdgcn_mfma_f32_16x16x32_f16(af[m], bf[n], acc[m][n], 0, 0, 0);
    }
    __syncthreads();
  }
#pragma unroll
  for (int n = 0; n < 4; ++n) {
    const int col = n0 + wc * 64 + n * 16 + lrow;
    const float bb = bias[col];
#pragma unroll
    for (int m = 0; m < 4; ++m) {
      const int rowb = m0 + wr * 64 + m * 16 + ((l >> 4) << 2);
#pragma unroll
      for (int r = 0; r < 4; ++r) {
        float v = acc[m][n][r] + bb;
        if (TANH) v = tanhf(v);
        C[(size_t)(rowb + r) * kG4 + col] = v;
      }
    }
  }
}

// ---------------- fp32 GEMM (heads only) ----------------
template <bool TANH>
__global__ __launch_bounds__(256) void gemm_kernel(
    const float* __restrict__ A, int lda,
    const float* __restrict__ W,
    const float* __restrict__ bias,
    float* __restrict__ C, int ldc, int N, int K) {
  __shared__ float As[8][128];
  __shared__ float Bs[8][128];
  const int tid = threadIdx.x;
  const int m0 = blockIdx.y * 128;
  const int n0 = blockIdx.x * 128;
  const int tx = tid & 15, ty = tid >> 4;
  const int lm = tid >> 1;
  const int lk = (tid & 1) * 4;
  float acc[8][8] = {};

  for (int k0 = 0; k0 < K; k0 += 8) {
    float4 av = *(const float4*)(A + (size_t)(m0 + lm) * lda + k0 + lk);
    const int n = n0 + lm;
    float4 bv = make_float4(0.f, 0.f, 0.f, 0.f);
    if (n < N) bv = *(const float4*)(W + (size_t)n * K + k0 + lk);
    __syncthreads();
    As[lk + 0][lm] = av.x; As[lk + 1][lm] = av.y;
    As[lk + 2][lm] = av.z; As[lk + 3][lm] = av.w;
    Bs[lk + 0][lm] = bv.x; Bs[lk + 1][lm] = bv.y;
    Bs[lk + 2][lm] = bv.z; Bs[lk + 3][lm] = bv.w;
    __syncthreads();
#pragma unroll
    for (int kk = 0; kk < 8; kk++) {
      float a[8], b8[8];
      *(float4*)&a[0]  = *(const float4*)&As[kk][ty * 8];
      *(float4*)&a[4]  = *(const float4*)&As[kk][ty * 8 + 4];
      *(float4*)&b8[0] = *(const float4*)&Bs[kk][tx * 8];
      *(float4*)&b8[4] = *(const float4*)&Bs[kk][tx * 8 + 4];
#pragma unroll
      for (int i = 0; i < 8; i++)
#pragma unroll
        for (int j = 0; j < 8; j++)
          acc[i][j] = fmaf(a[i], b8[j], acc[i][j]);
    }
  }
#pragma unroll
  for (int i = 0; i < 8; i++) {
    size_t m = m0 + ty * 8 + i;
#pragma unroll
    for (int j = 0; j < 8; j++) {
      int n = n0 + tx * 8 + j;
      if (n < N) {
        float v = acc[i][j] + bias[n];
        if (TANH) v = tanhf(v);
        C[m * ldc + n] = v;
      }
    }
  }
}

// ---------------- LSTM recurrence v4: pair-split, 1 barrier/step -----------
// grid 128: dir = bid&1, row = bid>>1. 512 threads: pair (t, t^1) owns
// column c = t>>1; thread computes ALL 4 gates of c over k-half kh = t&1.
// Weights: per gate 64 k-pairs of the half: 48 in VGPR (4x48 h2 = 192 regs,
// unified-file/AGPR as in round 4) + 16 in LDS (4x4 uint4, 128 KB total).
// Per step: 16 broadcast b128 h reads + 16 b128 weight reads + 256 dot2;
// combine halves via 4x shfl_xor(1); nonlin (exp-based) redundant in both
// lanes; even lane publishes h. h double-buffered -> single __syncthreads.
__global__ __launch_bounds__(512, 2) void lstm_rec_kernel(
    const float* __restrict__ xg_f, const float* __restrict__ xg_b,
    const float* __restrict__ Whh_f, const float* __restrict__ Whh_b,
    _Float16* __restrict__ out /* [B][S][512] fp16 */) {
  __shared__ uint4 wlds4[16 * 512];                    // 128 KB weight slice
  __shared__ __align__(16) _Float16 hbuf[2][kH];       // double-buffered h

  const int bid = blockIdx.x;
  const int dir = bid & 1;
  const int row = bid >> 1;
  const float* xg  = dir ? xg_b : xg_f;
  const float* Whh = dir ? Whh_b : Whh_f;
  const int t = threadIdx.x;
  const int c  = t >> 1;     // column 0..255
  const int kh = t & 1;      // k-half
  const int kbase = kh * 128;

  // ---- one-time: weights for 4 gates of column c, k in [kbase,kbase+128) --
  h2 wv[4][48];
#pragma unroll
  for (int g = 0; g < 4; ++g) {
    const float2* wr = (const float2*)(Whh + (size_t)(g * kH + c) * kH + kbase);
#pragma unroll
    for (int p = 0; p < 48; ++p) {
      float2 f = wr[p];
      h2 a; a.x = (_Float16)f.x; a.y = (_Float16)f.y;
      wv[g][p] = a;
    }
#pragma unroll
    for (int q = 0; q < 4; ++q) {
      unsigned u[4];
#pragma unroll
      for (int i = 0; i < 4; ++i) {
        float2 f = wr[48 + 4 * q + i];
        h2 a; a.x = (_Float16)f.x; a.y = (_Float16)f.y;
        u[i] = __builtin_bit_cast(unsigned, a);
      }
      wlds4[(g * 4 + q) * 512 + t] = make_uint4(u[0], u[1], u[2], u[3]);
    }
  }
  if (t < kH) hbuf[1][t] = (_Float16)0.f;   // step 0 reads hbuf[1]
  float c_state = 0.f;
  __syncthreads();

  const float* xgr = xg + (size_t)(row * kS) * kG4;
  const int sstep = dir ? -1 : 1;
  int s = dir ? (kS - 1) : 0;
  // current step's xg for the 4 gates of column c
  float x0 = xgr[(size_t)s * kG4 + c];
  float x1 = xgr[(size_t)s * kG4 + c + 256];
  float x2 = xgr[(size_t)s * kG4 + c + 512];
  float x3 = xgr[(size_t)s * kG4 + c + 768];

  for (int it = 0; it < kS; ++it) {
    // prefetch next step's xg (clamped addr; value unused on last iter)
    int sn = s + sstep; sn = sn < 0 ? 0 : (sn > kS - 1 ? kS - 1 : sn);
    const float* xnrow = xgr + (size_t)sn * kG4 + c;
    float xn0 = xnrow[0], xn1 = xnrow[256], xn2 = xnrow[512], xn3 = xnrow[768];

    // acc init: even lane carries xg (so shfl-combined sum counts it once)
    float a0 = kh ? 0.f : x0;
    float a1 = kh ? 0.f : x1;
    float a2 = kh ? 0.f : x2;
    float a3 = kh ? 0.f : x3;

    const uint4* hh = ((const uint4*)hbuf[(it & 1) ^ 1]) + kh * 16;
    // VGPR-resident weight pairs (p = 0..47)
#pragma unroll
    for (int u = 0; u < 12; ++u) {
      uint4 hv = hh[u];
      h2 h0 = __builtin_bit_cast(h2, hv.x);
      h2 h1 = __builtin_bit_cast(h2, hv.y);
      h2 hx = __builtin_bit_cast(h2, hv.z);
      h2 h3 = __builtin_bit_cast(h2, hv.w);
      a0 = dot2acc(wv[0][4*u+0], h0, a0); a0 = dot2acc(wv[0][4*u+1], h1, a0);
      a0 = dot2acc(wv[0][4*u+2], hx, a0); a0 = dot2acc(wv[0][4*u+3], h3, a0);
      a1 = dot2acc(wv[1][4*u+0], h0, a1); a1 = dot2acc(wv[1][4*u+1], h1, a1);
      a1 = dot2acc(wv[1][4*u+2], hx, a1); a1 = dot2acc(wv[1][4*u+3], h3, a1);
      a2 = dot2acc(wv[2][4*u+0], h0, a2); a2 = dot2acc(wv[2][4*u+1], h1, a2);
      a2 = dot2acc(wv[2][4*u+2], hx, a2); a2 = dot2acc(wv[2][4*u+3], h3, a2);
      a3 = dot2acc(wv[3][4*u+0], h0, a3); a3 = dot2acc(wv[3][4*u+1], h1, a3);
      a3 = dot2acc(wv[3][4*u+2], hx, a3); a3 = dot2acc(wv[3][4*u+3], h3, a3);
    }
    // LDS-resident weight pairs (p = 48..63)
#pragma unroll
    for (int q = 0; q < 4; ++q) {
      uint4 hv = hh[12 + q];
      h2 h0 = __builtin_bit_cast(h2, hv.x);
      h2 h1 = __builtin_bit_cast(h2, hv.y);
      h2 hx = __builtin_bit_cast(h2, hv.z);
      h2 h3 = __builtin_bit_cast(h2, hv.w);
      uint4 w0 = wlds4[(0 * 4 + q) * 512 + t];
      uint4 w1 = wlds4[(1 * 4 + q) * 512 + t];
      uint4 w2 = wlds4[(2 * 4 + q) * 512 + t];
      uint4 w3 = wlds4[(3 * 4 + q) * 512 + t];
      a0 = dot2acc(__builtin_bit_cast(h2, w0.x), h0, a0);
      a0 = dot2acc(__builtin_bit_cast(h2, w0.y), h1, a0);
      a0 = dot2acc(__builtin_bit_cast(h2, w0.z), hx, a0);
      a0 = dot2acc(__builtin_bit_cast(h2, w0.w), h3, a0);
      a1 = dot2acc(__builtin_bit_cast(h2, w1.x), h0, a1);
      a1 = dot2acc(__builtin_bit_cast(h2, w1.y), h1, a1);
      a1 = dot2acc(__builtin_bit_cast(h2, w1.z), hx, a1);
      a1 = dot2acc(__builtin_bit_cast(h2, w1.w), h3, a1);
      a2 = dot2acc(__builtin_bit_cast(h2, w2.x), h0, a2);
      a2 = dot2acc(__builtin_bit_cast(h2, w2.y), h1, a2);
      a2 = dot2acc(__builtin_bit_cast(h2, w2.z), hx, a2);
      a2 = dot2acc(__builtin_bit_cast(h2, w2.w), h3, a2);
      a3 = dot2acc(__builtin_bit_cast(h2, w3.x), h0, a3);
      a3 = dot2acc(__builtin_bit_cast(h2, w3.y), h1, a3);
      a3 = dot2acc(__builtin_bit_cast(h2, w3.z), hx, a3);
      a3 = dot2acc(__builtin_bit_cast(h2, w3.w), h3, a3);
    }
    // combine k-halves within the lane pair (same wave: lane ^ 1)
    float s0 = a0 + __shfl_xor(a0, 1);
    float s1 = a1 + __shfl_xor(a1, 1);
    float s2 = a2 + __shfl_xor(a2, 1);
    float s3 = a3 + __shfl_xor(a3, 1);
    // nonlinearity (redundant in both lanes; keeps c_state without exchange)
    float i_ = sigf(s0);
    float f_ = sigf(s1);
    float g_ = tanhfast(s2);
    float o_ = sigf(s3);
    c_state = f_ * c_state + i_ * g_;
    float h = o_ * tanhfast(c_state);
    if (!kh) {
      hbuf[it & 1][c] = (_Float16)h;
      out[((size_t)(row * kS + s)) * kLD + dir * kH + c] = (_Float16)h;
    }
    s += sstep;
    __syncthreads();
    x0 = xn0; x1 = xn1; x2 = xn2; x3 = xn3;
  }
}

// ---------------------------------------------------------------------------
extern "C" void kernel_launch(void* const* d_in, const int* in_sizes, int n_in,
                              void* d_out, int out_size, void* d_ws, size_t ws_size,
                              hipStream_t stream) {
  const int*   word_ids = (const int*)d_in[0];
  const int*   pos_ids  = (const int*)d_in[1];
  const int*   feat_idx = (const int*)d_in[2];
  const float* wlookup  = (const float*)d_in[3];
  const float* plookup  = (const float*)d_in[4];
  const float* Wih1f = (const float*)d_in[5];
  const float* Whh1f = (const float*)d_in[6];
  const float* bih1f = (const float*)d_in[7];
  const float* bhh1f = (const float*)d_in[8];
  const float* Wih1b = (const float*)d_in[9];
  const float* Whh1b = (const float*)d_in[10];
  const float* bih1b = (const float*)d_in[11];
  const float* bhh1b = (const float*)d_in[12];
  const float* Wih2f = (const float*)d_in[13];
  const float* Whh2f = (const float*)d_in[14];
  const float* bih2f = (const float*)d_in[15];
  const float* bhh2f = (const float*)d_in[16];
  const float* Wih2b = (const float*)d_in[17];
  const float* Whh2b = (const float*)d_in[18];
  const float* bih2b = (const float*)d_in[19];
  const float* bhh2b = (const float*)d_in[20];
  const float* hidLayer  = (const float*)d_in[21];
  const float* hidBias   = (const float*)d_in[22];
  const float* outLayer  = (const float*)d_in[23];
  const float* outBias   = (const float*)d_in[24];
  const float* rhidLayer = (const float*)d_in[25];
  const float* rhidBias  = (const float*)d_in[26];
  const float* routLayer = (const float*)d_in[27];
  const float* routBias  = (const float*)d_in[28];

  float* ws = (float*)d_ws;
  // workspace layout (float units; fp16 buffers counted as half-floats)
  const size_t F_IVECH = 0;
  const size_t F_XGF   = F_IVECH + (size_t)kTok * 192 / 2;
  const size_t F_XGB   = F_XGF + (size_t)kTok * kG4;         // fp32
  const size_t F_V1H   = F_XGB + (size_t)kTok * kG4;
  const size_t F_V2H   = F_V1H + (size_t)kTok * kLD / 2;
  const size_t F_WHA   = F_V2H + (size_t)kTok * kLD / 2;
  const size_t F_WHB   = F_WHA + (size_t)2 * kG4 * 192 / 2;
  const size_t F_WHID  = F_WHB + (size_t)2 * kG4 * 512 / 2;
  const size_t F_BSUM  = F_WHID + (size_t)kG4 * 6144 / 2;
  const size_t F_HB    = F_BSUM + 4 * kG4;
  const size_t F_END   = F_HB + kG4;
  const size_t F_HID   = F_XGF;                              // overlay after rec L2
  if (ws_size < F_END * sizeof(float)) return;

  _Float16* ivec_h = (_Float16*)(ws + F_IVECH);
  float*    xg_f   = ws + F_XGF;
  float*    xg_b   = ws + F_XGB;
  _Float16* vec1h  = (_Float16*)(ws + F_V1H);
  _Float16* vec2h  = (_Float16*)(ws + F_V2H);
  _Float16* whA    = (_Float16*)(ws + F_WHA);
  _Float16* whB    = (_Float16*)(ws + F_WHB);
  _Float16* whid   = (_Float16*)(ws + F_WHID);
  float*    bsum   = ws + F_BSUM;
  float*    hb     = ws + F_HB;
  float*    hidc   = ws + F_HID;
  float*    outp   = (float*)d_out;

  // 1. weight/bias prep + embeddings
  prep_bias<<<16, 256, 0, stream>>>(bih1f, bhh1f, bih1b, bhh1b,
                                    bih2f, bhh2f, bih2b, bhh2b, bsum);
  concat_bias<<<4, 256, 0, stream>>>(hidBias, rhidBias, hb);
  f2h_pad<<<(1024 * 48 + 255) / 256, 256, 0, stream>>>(Wih1f, whA, 1024, 160, 192);
  f2h_pad<<<(1024 * 48 + 255) / 256, 256, 0, stream>>>(Wih1b, whA + 1024 * 192, 1024, 160, 192);
  f2h_pad<<<(1024 * 128 + 255) / 256, 256, 0, stream>>>(Wih2f, whB, 1024, 512, 512);
  f2h_pad<<<(1024 * 128 + 255) / 256, 256, 0, stream>>>(Wih2b, whB + 1024 * 512, 1024, 512, 512);
  f2h_pad<<<(512 * 1536 + 255) / 256, 256, 0, stream>>>(hidLayer, whid, 512, 6144, 6144);
  f2h_pad<<<(512 * 1536 + 255) / 256, 256, 0, stream>>>(rhidLayer, whid + (size_t)512 * 6144,
                                                        512, 6144, 6144);
  embed_h<<<(kTok * 24 + 255) / 256, 256, 0, stream>>>(word_ids, pos_ids,
                                                       wlookup, plookup, ivec_h);
  // 2. layer-1 input gates (K=192, zero-padded)
  mfma_gemm<false, false><<<dim3(8, 128), 256, 0, stream>>>(
      ivec_h, 192, whA, bsum + 0, nullptr, nullptr, xg_f, 192);
  mfma_gemm<false, false><<<dim3(8, 128), 256, 0, stream>>>(
      ivec_h, 192, whA + 1024 * 192, bsum + 1024, nullptr, nullptr, xg_b, 192);
  // 3. layer-1 recurrence -> fp16
  lstm_rec_kernel<<<128, 512, 0, stream>>>(xg_f, xg_b, Whh1f, Whh1b, vec1h);
  // 4. layer-2 input gates (K=512)
  mfma_gemm<false, false><<<dim3(8, 128), 256, 0, stream>>>(
      vec1h, 512, whB, bsum + 2048, nullptr, nullptr, xg_f, 512);
  mfma_gemm<false, false><<<dim3(8, 128), 256, 0, stream>>>(
      vec1h, 512, whB + 1024 * 512, bsum + 3072, nullptr, nullptr, xg_b, 512);
  // 5. layer-2 recurrence -> fp16
  lstm_rec_kernel<<<128, 512, 0, stream>>>(xg_f, xg_b, Whh2f, Whh2b, vec2h);
  // 6. gather + hid/rhid MFMA GEMM with tanh (K=6144)
  mfma_gemm<true, true><<<dim3(8, 128), 256, 0, stream>>>(
      nullptr, 0, whid, hb, vec2h, feat_idx, hidc, 6144);
  // 7. output heads (fp32) -> d_out: out [B,T,3] then rout [B,T,93]
  gemm_kernel<false><<<dim3(1, 128), 256, 0, stream>>>(
      hidc, kG4, outLayer, outBias, outp, 3, 3, 512);
  gemm_kernel<false><<<dim3(1, 128), 256, 0, stream>>>(
      hidc + 512, kG4, routLayer, routBias, outp + (size_t)kTok * 3, 93, 93, 512);
}

// Round 6
// 1640.860 us; speedup vs baseline: 7.0389x; 1.0136x over previous
//
#include <hip/hip_runtime.h>
#include <hip/hip_fp16.h>
#include <math.h>

// ---------------------------------------------------------------------------
// ArcHybridLSTM forward on MI355X — round 6: DPP combine + xg swizzle + MFMA heads.
//   1. embed_h:      ivec_h[B*S,192] fp16 (160 real + 32 zero-pad)
//   2. mfma_gemm<.,1>: xgs = swizzled(ivec_h @ Wih^T + bias)  [B*S][c*4+gate] f32
//   3. lstm_rec L1:  -> vec1h[B*S,512] fp16
//   4. mfma_gemm<.,1>: xgs2 (K=512)
//   5. lstm_rec L2:  -> vec2h fp16
//   6. mfma_gemm<true,2>: hidc_h[B*S,1024] fp16 = tanh(feats@[hid|rhid]^T+b)
//   7. mfma_gemm<false,3>: heads via W96=[outLayer|0 ; 0|routLayer] (K=1024)
//      -> d_out (out [B,T,3] ++ rout [B,T,93]); fp32 head gemms deleted
//      (round-5 counters: one showed a 40ms outlier + 2.6e6 bank conflicts).
//
// lstm v5 = v4 + (a) DPP quad-perm pair-combine instead of __shfl_xor
// (ds_bpermute -> VALU; -4 LDS-pipe ops/thr/step), (b) xg swizzled so the
// 4 gates of column c are ONE float4 (4 VMEM loads -> 1). Weight storage
// unchanged (192 h2 VGPR + 128KB LDS slice; LDS-inst floor ~3000cyc/step).
// ---------------------------------------------------------------------------

namespace {
constexpr int kB = 64, kS = 256, kH = 256, kG4 = 1024;   // batch, seq, hidden, 4H
constexpr int kLD = 512;                                 // LSTM concat dim
constexpr int kTok = kB * kS;                            // 16384 rows everywhere
}

typedef _Float16 h2 __attribute__((ext_vector_type(2)));
typedef _Float16 h4 __attribute__((ext_vector_type(4)));
typedef _Float16 h8 __attribute__((ext_vector_type(8)));
typedef float f4 __attribute__((ext_vector_type(4)));

#if __has_builtin(__builtin_amdgcn_fdot2)
#define USE_FDOT2 1
#else
#define USE_FDOT2 0
#endif

__device__ __forceinline__ float dot2acc(h2 w, h2 hh, float acc) {
#if USE_FDOT2
  return __builtin_amdgcn_fdot2(w, hh, acc, false);
#else
  return fmaf((float)w.x, (float)hh.x, fmaf((float)w.y, (float)hh.y, acc));
#endif
}

__device__ __forceinline__ float fastrcp(float x) {
#if __has_builtin(__builtin_amdgcn_rcpf)
  return __builtin_amdgcn_rcpf(x);
#else
  return 1.f / x;
#endif
}
__device__ __forceinline__ float sigf(float x) { return fastrcp(1.f + __expf(-x)); }
__device__ __forceinline__ float tanhfast(float x) {
  float u = __expf(2.f * x);
  return 1.f - 2.f * fastrcp(u + 1.f);
}

// pair-combine: x + (x from lane^1), VALU-pipe via DPP quad_perm [1,0,3,2]
__device__ __forceinline__ float dppadd1(float x) {
#if __has_builtin(__builtin_amdgcn_mov_dpp)
  int y = __builtin_amdgcn_mov_dpp(__builtin_bit_cast(int, x), 0xB1, 0xF, 0xF, true);
  return x + __builtin_bit_cast(float, y);
#else
  return x + __shfl_xor(x, 1);
#endif
}

// 16B global->LDS stage. lds_base must be wave-uniform; lane writes base+l*16.
__device__ __forceinline__ void stage16(const void* g, void* lds_base, int lane) {
#if __has_builtin(__builtin_amdgcn_global_load_lds)
  (void)lane;
  __builtin_amdgcn_global_load_lds((const __attribute__((address_space(1))) void*)g,
                                   (__attribute__((address_space(3))) void*)lds_base,
                                   16, 0, 0);
#else
  *(uint4*)((char*)lds_base + lane * 16) = *(const uint4*)g;
#endif
}

// ---------------- embeddings -> fp16, K padded 160->192 ----------------
__global__ void embed_h(const int* __restrict__ wid, const int* __restrict__ pid,
                        const float* __restrict__ wl, const float* __restrict__ pl,
                        _Float16* __restrict__ dst) {
  int tid = blockIdx.x * blockDim.x + threadIdx.x;  // kTok * 24 chunks of 8 cols
  if (tid >= kTok * 24) return;
  int tok = tid / 24, c8 = tid % 24;
  h8 o;
  if (c8 < 20) {
    const float* src = (c8 < 16) ? (wl + (size_t)wid[tok] * 128 + c8 * 8)
                                 : (pl + (size_t)pid[tok] * 32 + (c8 - 16) * 8);
    float4 v0 = *(const float4*)src;
    float4 v1 = *(const float4*)(src + 4);
    o[0] = (_Float16)v0.x; o[1] = (_Float16)v0.y;
    o[2] = (_Float16)v0.z; o[3] = (_Float16)v0.w;
    o[4] = (_Float16)v1.x; o[5] = (_Float16)v1.y;
    o[6] = (_Float16)v1.z; o[7] = (_Float16)v1.w;
  } else {
    o = (h8)(_Float16)0.f;
  }
  *(h8*)(dst + (size_t)tok * 192 + c8 * 8) = o;
}

// ---------------- fp32 -> fp16 with K zero-pad ----------------
__global__ void f2h_pad(const float* __restrict__ src, _Float16* __restrict__ dst,
                        int rows, int Kin, int Kpad) {
  int per = Kpad >> 2;
  int tid = blockIdx.x * blockDim.x + threadIdx.x;
  if (tid >= rows * per) return;
  int row = tid / per, c4 = (tid % per) << 2;
  h4 o;
  if (c4 < Kin) {
    float4 v = *(const float4*)(src + (size_t)row * Kin + c4);
    o[0] = (_Float16)v.x; o[1] = (_Float16)v.y;
    o[2] = (_Float16)v.z; o[3] = (_Float16)v.w;
  } else {
    o = (h4)(_Float16)0.f;
  }
  *(h4*)(dst + (size_t)row * Kpad + c4) = o;
}

// ---------------- bias sums (bih+bhh per layer/dir) ----------------
__global__ void prep_bias(const float* __restrict__ b0, const float* __restrict__ b1,
                          const float* __restrict__ b2, const float* __restrict__ b3,
                          const float* __restrict__ b4, const float* __restrict__ b5,
                          const float* __restrict__ b6, const float* __restrict__ b7,
                          float* __restrict__ bsum) {
  int tid = blockIdx.x * blockDim.x + threadIdx.x;
  if (tid >= 4 * kG4) return;
  int grp = tid >> 10, i = tid & 1023;
  const float* x; const float* y;
  switch (grp) {
    case 0: x = b0; y = b1; break;
    case 1: x = b2; y = b3; break;
    case 2: x = b4; y = b5; break;
    default: x = b6; y = b7; break;
  }
  bsum[tid] = x[i] + y[i];
}

__global__ void concat_bias(const float* __restrict__ a, const float* __restrict__ b,
                            float* __restrict__ dst) {
  int tid = blockIdx.x * blockDim.x + threadIdx.x;
  if (tid >= kG4) return;
  dst[tid] = (tid < 512) ? a[tid] : b[tid - 512];
}

// ---------------- heads weight: W96[128][1024] = [outL|0 ; 0|routL] --------
__global__ void build_w96(const float* __restrict__ outL, const float* __restrict__ outB,
                          const float* __restrict__ routL, const float* __restrict__ routB,
                          _Float16* __restrict__ w, float* __restrict__ b) {
  int tid = blockIdx.x * blockDim.x + threadIdx.x;  // 128*1024
  if (tid >= 128 * 1024) return;
  int n = tid >> 10, k = tid & 1023;
  float v = 0.f;
  if (n < 3) { if (k < 512) v = outL[n * 512 + k]; }
  else if (n < 96) { if (k >= 512) v = routL[(size_t)(n - 3) * 512 + (k - 512)]; }
  w[tid] = (_Float16)v;
  if (k == 0) b[n] = (n < 3) ? outB[n] : (n < 96 ? routB[n - 3] : 0.f);
}

// ---------------- f16 MFMA GEMM: C = act(A @ W^T + bias) -------------------
// CMODE 0: fp32 C[row*1024+col]          (unused now, kept for clarity)
// CMODE 1: fp32 xg-swizzled: col' = (col&255)*4 + (col>>8)
// CMODE 2: fp16 C, tanh applied           (gather -> hidc_h)
// CMODE 3: heads: col<3 -> out[row*3+col]; 3<=col<96 -> rout[row*93+col-3]
template <bool GATHER, int CMODE>
__global__ __launch_bounds__(256) void mfma_gemm(
    const _Float16* __restrict__ A, int lda,
    const _Float16* __restrict__ W,
    const float* __restrict__ bias,
    const _Float16* __restrict__ vsrc, const int* __restrict__ fidx,
    void* __restrict__ C, int K) {
  __shared__ _Float16 Asm[128 * 64];  // 16 KB
  __shared__ _Float16 Bsm[128 * 64];  // 16 KB
  const int tid = threadIdx.x;
  const int w = tid >> 6, l = tid & 63;
  const int wr = w >> 1, wc = w & 1;
  const int m0 = blockIdx.y * 128, n0 = blockIdx.x * 128;
  const int lrow = l & 15, lk8 = (l >> 4) << 3;
  const int stg_r = l >> 3;
  const int stg_c = (l & 7) ^ stg_r;

  f4 acc[4][4] = {};

  for (int k0 = 0; k0 < K; k0 += 64) {
#pragma unroll
    for (int ii = 0; ii < 4; ++ii) {
      const int r = w * 32 + ii * 8 + stg_r;
      const _Float16* ga;
      if (GATHER) {
        const int token = m0 + r;
        const int slot = k0 >> 9;
        const int idx = fidx[token * 12 + slot];
        ga = vsrc + ((((size_t)(token >> 8) << 8) + idx) << 9) + (k0 & 511) + (stg_c << 3);
      } else {
        ga = A + (size_t)(m0 + r) * lda + k0 + (stg_c << 3);
      }
      stage16(ga, &Asm[(size_t)(w * 32 + ii * 8) * 64], l);
      const _Float16* gb = W + (size_t)(n0 + r) * K + k0 + (stg_c << 3);
      stage16(gb, &Bsm[(size_t)(w * 32 + ii * 8) * 64], l);
    }
    __syncthreads();
#pragma unroll
    for (int kk = 0; kk < 64; kk += 32) {
      const int c0 = (kk + lk8) >> 3;
      h8 af[4], bf[4];
#pragma unroll
      for (int m = 0; m < 4; ++m) {
        const int row = wr * 64 + m * 16 + lrow;
        af[m] = *(const h8*)&Asm[row * 64 + ((c0 ^ (row & 7)) << 3)];
      }
#pragma unroll
      for (int n = 0; n < 4; ++n) {
        const int row = wc * 64 + n * 16 + lrow;
        bf[n] = *(const h8*)&Bsm[row * 64 + ((c0 ^ (row & 7)) << 3)];
      }
#pragma unroll
      for (int m = 0; m < 4; ++m)
#pragma unroll
        for (int n = 0; n < 4; ++n)
          acc[m][n] = __builtin_amdgcn_mfma_f32_16x16x32_f16(af[m], bf[n], acc[m][n], 0, 0, 0);
    }
    __syncthreads();
  }
  // epilogue: C/D layout col=lane&15, row=(lane>>4)*4+reg (m89/m91)
#pragma unroll
  for (int n = 0; n < 4; ++n) {
    const int col = n0 + wc * 64 + n * 16 + lrow;
    const float bb = bias[col];
#pragma unroll
    for (int m = 0; m < 4; ++m) {
      const int rowb = m0 + wr * 64 + m * 16 + ((l >> 4) << 2);
#pragma unroll
      for (int r = 0; r < 4; ++r) {
        float v = acc[m][n][r] + bb;
        const size_t row = rowb + r;
        if (CMODE == 0) {
          ((float*)C)[row * kG4 + col] = v;
        } else if (CMODE == 1) {
          ((float*)C)[row * kG4 + ((col & 255) * 4 + (col >> 8))] = v;
        } else if (CMODE == 2) {
          ((_Float16*)C)[row * kG4 + col] = (_Float16)tanhf(v);
        } else {
          if (col < 3)       ((float*)C)[row * 3 + col] = v;
          else if (col < 96) ((float*)C)[(size_t)kTok * 3 + row * 93 + (col - 3)] = v;
        }
      }
    }
  }
}

// ---------------- LSTM recurrence v5: DPP combine, float4 xg ---------------
// grid 128: dir = bid&1, row = bid>>1. 512 threads: pair (t, t^1) owns
// column c = t>>1; thread computes ALL 4 gates of c over k-half kh = t&1.
// xg pre-swizzled by the producer: the 4 gates of column c = one float4 at
// xgs[token*1024 + 4c]. Pair combine via DPP quad_perm (VALU pipe).
// Weights: 4x48 h2 in VGPR + 4x4 uint4 in LDS (128KB slice).
__global__ __launch_bounds__(512, 2) void lstm_rec_kernel(
    const float* __restrict__ xg_f, const float* __restrict__ xg_b,
    const float* __restrict__ Whh_f, const float* __restrict__ Whh_b,
    _Float16* __restrict__ out /* [B][S][512] fp16 */) {
  __shared__ uint4 wlds4[16 * 512];                    // 128 KB weight slice
  __shared__ __align__(16) _Float16 hbuf[2][kH];       // double-buffered h

  const int bid = blockIdx.x;
  const int dir = bid & 1;
  const int row = bid >> 1;
  const float* xg  = dir ? xg_b : xg_f;
  const float* Whh = dir ? Whh_b : Whh_f;
  const int t = threadIdx.x;
  const int c  = t >> 1;     // column 0..255
  const int kh = t & 1;      // k-half
  const int kbase = kh * 128;

  // ---- one-time: weights for 4 gates of column c, k in [kbase,kbase+128) --
  h2 wv[4][48];
#pragma unroll
  for (int g = 0; g < 4; ++g) {
    const float2* wr = (const float2*)(Whh + (size_t)(g * kH + c) * kH + kbase);
#pragma unroll
    for (int p = 0; p < 48; ++p) {
      float2 f = wr[p];
      h2 a; a.x = (_Float16)f.x; a.y = (_Float16)f.y;
      wv[g][p] = a;
    }
#pragma unroll
    for (int q = 0; q < 4; ++q) {
      unsigned u[4];
#pragma unroll
      for (int i = 0; i < 4; ++i) {
        float2 f = wr[48 + 4 * q + i];
        h2 a; a.x = (_Float16)f.x; a.y = (_Float16)f.y;
        u[i] = __builtin_bit_cast(unsigned, a);
      }
      wlds4[(g * 4 + q) * 512 + t] = make_uint4(u[0], u[1], u[2], u[3]);
    }
  }
  if (t < kH) hbuf[1][t] = (_Float16)0.f;   // step 0 reads hbuf[1]
  float c_state = 0.f;
  __syncthreads();

  const float* xgr = xg + (size_t)(row * kS) * kG4;
  const int sstep = dir ? -1 : 1;
  int s = dir ? (kS - 1) : 0;
  float4 xv = *(const float4*)(xgr + (size_t)s * kG4 + 4 * c);

  for (int it = 0; it < kS; ++it) {
    // prefetch next step's xg (clamped addr; value unused on last iter)
    int sn = s + sstep; sn = sn < 0 ? 0 : (sn > kS - 1 ? kS - 1 : sn);
    float4 xvn = *(const float4*)(xgr + (size_t)sn * kG4 + 4 * c);

    // acc init: even lane carries xg (counted once after DPP combine)
    float a0 = kh ? 0.f : xv.x;
    float a1 = kh ? 0.f : xv.y;
    float a2 = kh ? 0.f : xv.z;
    float a3 = kh ? 0.f : xv.w;

    const uint4* hh = ((const uint4*)hbuf[(it & 1) ^ 1]) + kh * 16;
    // VGPR-resident weight pairs (p = 0..47)
#pragma unroll
    for (int u = 0; u < 12; ++u) {
      uint4 hv = hh[u];
      h2 h0 = __builtin_bit_cast(h2, hv.x);
      h2 h1 = __builtin_bit_cast(h2, hv.y);
      h2 hx = __builtin_bit_cast(h2, hv.z);
      h2 h3 = __builtin_bit_cast(h2, hv.w);
      a0 = dot2acc(wv[0][4*u+0], h0, a0); a0 = dot2acc(wv[0][4*u+1], h1, a0);
      a0 = dot2acc(wv[0][4*u+2], hx, a0); a0 = dot2acc(wv[0][4*u+3], h3, a0);
      a1 = dot2acc(wv[1][4*u+0], h0, a1); a1 = dot2acc(wv[1][4*u+1], h1, a1);
      a1 = dot2acc(wv[1][4*u+2], hx, a1); a1 = dot2acc(wv[1][4*u+3], h3, a1);
      a2 = dot2acc(wv[2][4*u+0], h0, a2); a2 = dot2acc(wv[2][4*u+1], h1, a2);
      a2 = dot2acc(wv[2][4*u+2], hx, a2); a2 = dot2acc(wv[2][4*u+3], h3, a2);
      a3 = dot2acc(wv[3][4*u+0], h0, a3); a3 = dot2acc(wv[3][4*u+1], h1, a3);
      a3 = dot2acc(wv[3][4*u+2], hx, a3); a3 = dot2acc(wv[3][4*u+3], h3, a3);
    }
    // LDS-resident weight pairs (p = 48..63)
#pragma unroll
    for (int q = 0; q < 4; ++q) {
      uint4 hv = hh[12 + q];
      h2 h0 = __builtin_bit_cast(h2, hv.x);
      h2 h1 = __builtin_bit_cast(h2, hv.y);
      h2 hx = __builtin_bit_cast(h2, hv.z);
      h2 h3 = __builtin_bit_cast(h2, hv.w);
      uint4 w0 = wlds4[(0 * 4 + q) * 512 + t];
      uint4 w1 = wlds4[(1 * 4 + q) * 512 + t];
      uint4 w2 = wlds4[(2 * 4 + q) * 512 + t];
      uint4 w3 = wlds4[(3 * 4 + q) * 512 + t];
      a0 = dot2acc(__builtin_bit_cast(h2, w0.x), h0, a0);
      a0 = dot2acc(__builtin_bit_cast(h2, w0.y), h1, a0);
      a0 = dot2acc(__builtin_bit_cast(h2, w0.z), hx, a0);
      a0 = dot2acc(__builtin_bit_cast(h2, w0.w), h3, a0);
      a1 = dot2acc(__builtin_bit_cast(h2, w1.x), h0, a1);
      a1 = dot2acc(__builtin_bit_cast(h2, w1.y), h1, a1);
      a1 = dot2acc(__builtin_bit_cast(h2, w1.z), hx, a1);
      a1 = dot2acc(__builtin_bit_cast(h2, w1.w), h3, a1);
      a2 = dot2acc(__builtin_bit_cast(h2, w2.x), h0, a2);
      a2 = dot2acc(__builtin_bit_cast(h2, w2.y), h1, a2);
      a2 = dot2acc(__builtin_bit_cast(h2, w2.z), hx, a2);
      a2 = dot2acc(__builtin_bit_cast(h2, w2.w), h3, a2);
      a3 = dot2acc(__builtin_bit_cast(h2, w3.x), h0, a3);
      a3 = dot2acc(__builtin_bit_cast(h2, w3.y), h1, a3);
      a3 = dot2acc(__builtin_bit_cast(h2, w3.z), hx, a3);
      a3 = dot2acc(__builtin_bit_cast(h2, w3.w), h3, a3);
    }
    // combine k-halves within the lane pair — DPP (VALU pipe, no LDS)
    float s0 = dppadd1(a0);
    float s1 = dppadd1(a1);
    float s2 = dppadd1(a2);
    float s3 = dppadd1(a3);
    // nonlinearity (redundant in both lanes; keeps c_state without exchange)
    float i_ = sigf(s0);
    float f_ = sigf(s1);
    float g_ = tanhfast(s2);
    float o_ = sigf(s3);
    c_state = f_ * c_state + i_ * g_;
    float h = o_ * tanhfast(c_state);
    if (!kh) {
      hbuf[it & 1][c] = (_Float16)h;
      out[((size_t)(row * kS + s)) * kLD + dir * kH + c] = (_Float16)h;
    }
    s += sstep;
    __syncthreads();
    xv = xvn;
  }
}

// ---------------------------------------------------------------------------
extern "C" void kernel_launch(void* const* d_in, const int* in_sizes, int n_in,
                              void* d_out, int out_size, void* d_ws, size_t ws_size,
                              hipStream_t stream) {
  const int*   word_ids = (const int*)d_in[0];
  const int*   pos_ids  = (const int*)d_in[1];
  const int*   feat_idx = (const int*)d_in[2];
  const float* wlookup  = (const float*)d_in[3];
  const float* plookup  = (const float*)d_in[4];
  const float* Wih1f = (const float*)d_in[5];
  const float* Whh1f = (const float*)d_in[6];
  const float* bih1f = (const float*)d_in[7];
  const float* bhh1f = (const float*)d_in[8];
  const float* Wih1b = (const float*)d_in[9];
  const float* Whh1b = (const float*)d_in[10];
  const float* bih1b = (const float*)d_in[11];
  const float* bhh1b = (const float*)d_in[12];
  const float* Wih2f = (const float*)d_in[13];
  const float* Whh2f = (const float*)d_in[14];
  const float* bih2f = (const float*)d_in[15];
  const float* bhh2f = (const float*)d_in[16];
  const float* Wih2b = (const float*)d_in[17];
  const float* Whh2b = (const float*)d_in[18];
  const float* bih2b = (const float*)d_in[19];
  const float* bhh2b = (const float*)d_in[20];
  const float* hidLayer  = (const float*)d_in[21];
  const float* hidBias   = (const float*)d_in[22];
  const float* outLayer  = (const float*)d_in[23];
  const float* outBias   = (const float*)d_in[24];
  const float* rhidLayer = (const float*)d_in[25];
  const float* rhidBias  = (const float*)d_in[26];
  const float* routLayer = (const float*)d_in[27];
  const float* routBias  = (const float*)d_in[28];

  float* ws = (float*)d_ws;
  // workspace layout (float units; fp16 buffers counted as half-floats)
  const size_t F_IVECH = 0;
  const size_t F_XGF   = F_IVECH + (size_t)kTok * 192 / 2;
  const size_t F_XGB   = F_XGF + (size_t)kTok * kG4;         // fp32 (swizzled)
  const size_t F_V1H   = F_XGB + (size_t)kTok * kG4;
  const size_t F_V2H   = F_V1H + (size_t)kTok * kLD / 2;
  const size_t F_WHA   = F_V2H + (size_t)kTok * kLD / 2;
  const size_t F_WHB   = F_WHA + (size_t)2 * kG4 * 192 / 2;
  const size_t F_WHID  = F_WHB + (size_t)2 * kG4 * 512 / 2;
  const size_t F_BSUM  = F_WHID + (size_t)kG4 * 6144 / 2;
  const size_t F_HB    = F_BSUM + 4 * kG4;
  const size_t F_W96   = F_HB + kG4;
  const size_t F_B96   = F_W96 + (size_t)128 * kG4 / 2;
  const size_t F_END   = F_B96 + 128;
  const size_t F_HID   = F_XGF;                              // overlay after rec L2
  if (ws_size < F_END * sizeof(float)) return;

  _Float16* ivec_h = (_Float16*)(ws + F_IVECH);
  float*    xgs_f  = ws + F_XGF;
  float*    xgs_b  = ws + F_XGB;
  _Float16* vec1h  = (_Float16*)(ws + F_V1H);
  _Float16* vec2h  = (_Float16*)(ws + F_V2H);
  _Float16* whA    = (_Float16*)(ws + F_WHA);
  _Float16* whB    = (_Float16*)(ws + F_WHB);
  _Float16* whid   = (_Float16*)(ws + F_WHID);
  float*    bsum   = ws + F_BSUM;
  float*    hb     = ws + F_HB;
  _Float16* w96    = (_Float16*)(ws + F_W96);
  float*    b96    = ws + F_B96;
  _Float16* hidc_h = (_Float16*)(ws + F_HID);
  float*    outp   = (float*)d_out;

  // 1. weight/bias prep + embeddings
  prep_bias<<<16, 256, 0, stream>>>(bih1f, bhh1f, bih1b, bhh1b,
                                    bih2f, bhh2f, bih2b, bhh2b, bsum);
  concat_bias<<<4, 256, 0, stream>>>(hidBias, rhidBias, hb);
  build_w96<<<512, 256, 0, stream>>>(outLayer, outBias, routLayer, routBias, w96, b96);
  f2h_pad<<<(1024 * 48 + 255) / 256, 256, 0, stream>>>(Wih1f, whA, 1024, 160, 192);
  f2h_pad<<<(1024 * 48 + 255) / 256, 256, 0, stream>>>(Wih1b, whA + 1024 * 192, 1024, 160, 192);
  f2h_pad<<<(1024 * 128 + 255) / 256, 256, 0, stream>>>(Wih2f, whB, 1024, 512, 512);
  f2h_pad<<<(1024 * 128 + 255) / 256, 256, 0, stream>>>(Wih2b, whB + 1024 * 512, 1024, 512, 512);
  f2h_pad<<<(512 * 1536 + 255) / 256, 256, 0, stream>>>(hidLayer, whid, 512, 6144, 6144);
  f2h_pad<<<(512 * 1536 + 255) / 256, 256, 0, stream>>>(rhidLayer, whid + (size_t)512 * 6144,
                                                        512, 6144, 6144);
  embed_h<<<(kTok * 24 + 255) / 256, 256, 0, stream>>>(word_ids, pos_ids,
                                                       wlookup, plookup, ivec_h);
  // 2. layer-1 input gates (K=192, zero-padded), xg-swizzled output
  mfma_gemm<false, 1><<<dim3(8, 128), 256, 0, stream>>>(
      ivec_h, 192, whA, bsum + 0, nullptr, nullptr, xgs_f, 192);
  mfma_gemm<false, 1><<<dim3(8, 128), 256, 0, stream>>>(
      ivec_h, 192, whA + 1024 * 192, bsum + 1024, nullptr, nullptr, xgs_b, 192);
  // 3. layer-1 recurrence -> fp16
  lstm_rec_kernel<<<128, 512, 0, stream>>>(xgs_f, xgs_b, Whh1f, Whh1b, vec1h);
  // 4. layer-2 input gates (K=512), xg-swizzled output
  mfma_gemm<false, 1><<<dim3(8, 128), 256, 0, stream>>>(
      vec1h, 512, whB, bsum + 2048, nullptr, nullptr, xgs_f, 512);
  mfma_gemm<false, 1><<<dim3(8, 128), 256, 0, stream>>>(
      vec1h, 512, whB + 1024 * 512, bsum + 3072, nullptr, nullptr, xgs_b, 512);
  // 5. layer-2 recurrence -> fp16
  lstm_rec_kernel<<<128, 512, 0, stream>>>(xgs_f, xgs_b, Whh2f, Whh2b, vec2h);
  // 6. gather + hid/rhid MFMA GEMM with tanh (K=6144) -> fp16 hidc
  mfma_gemm<true, 2><<<dim3(8, 128), 256, 0, stream>>>(
      nullptr, 0, whid, hb, vec2h, feat_idx, hidc_h, 6144);
  // 7. heads: one MFMA GEMM, K=1024, N-tile 128 (cols 0-2 out, 3-95 rout)
  mfma_gemm<false, 3><<<dim3(1, 128), 256, 0, stream>>>(
      hidc_h, kG4, w96, b96, nullptr, nullptr, outp, kG4);
}

// Round 7
// 1530.575 us; speedup vs baseline: 7.5461x; 1.0721x over previous
//
#include <hip/hip_runtime.h>
#include <hip/hip_fp16.h>
#include <math.h>

// ---------------------------------------------------------------------------
// ArcHybridLSTM forward on MI355X — round 7: lstm VGPR-rebalance + 256-tile gather.
//   1. embed_h:      ivec_h[B*S,192] fp16 (160 real + 32 zero-pad)
//   2. mfma_gemm<.,1>: xgs = swizzled(ivec_h @ Wih^T + bias)  [B*S][c*4+gate] f32
//   3. lstm_rec L1:  -> vec1h[B*S,512] fp16
//   4. mfma_gemm<.,1>: xgs2 (K=512)
//   5. lstm_rec L2:  -> vec2h fp16
//   6. mfma_gemm_g256: hidc_h = tanh(feats@[hid|rhid]^T+b), K=6144, 256x128 tile
//   7. mfma_gemm<false,3>: heads via W96 (K=1024) -> d_out
//
// lstm v6 (from round-6 counters: LDS-pipe-bound, 1.678e7 bank conflicts =
// dropped v3 swizzle, only 128/256 VGPRs used):
//   - weight split 96->208 VGPR regs (52 pairs/gate), LDS slice 128->96 KB
//     (12 pairs/gate) => weight ds_read_b128 16 -> 12 per thread per step
//   - restore t^((t>>3)&7) swizzle on the LDS weight slice (v3 had 0 conflicts)
//   - xg loaded in-loop, added after the DPP combine (frees prefetch regs)
// gather GEMM: 256x128 tile, 8 waves 4x2 (W panel traffic halved vs 128x128).
// ---------------------------------------------------------------------------

namespace {
constexpr int kB = 64, kS = 256, kH = 256, kG4 = 1024;   // batch, seq, hidden, 4H
constexpr int kLD = 512;                                 // LSTM concat dim
constexpr int kTok = kB * kS;                            // 16384 rows everywhere
}

typedef _Float16 h2 __attribute__((ext_vector_type(2)));
typedef _Float16 h4 __attribute__((ext_vector_type(4)));
typedef _Float16 h8 __attribute__((ext_vector_type(8)));
typedef float f4 __attribute__((ext_vector_type(4)));

#if __has_builtin(__builtin_amdgcn_fdot2)
#define USE_FDOT2 1
#else
#define USE_FDOT2 0
#endif

__device__ __forceinline__ float dot2acc(h2 w, h2 hh, float acc) {
#if USE_FDOT2
  return __builtin_amdgcn_fdot2(w, hh, acc, false);
#else
  return fmaf((float)w.x, (float)hh.x, fmaf((float)w.y, (float)hh.y, acc));
#endif
}

__device__ __forceinline__ float fastrcp(float x) {
#if __has_builtin(__builtin_amdgcn_rcpf)
  return __builtin_amdgcn_rcpf(x);
#else
  return 1.f / x;
#endif
}
__device__ __forceinline__ float sigf(float x) { return fastrcp(1.f + __expf(-x)); }
__device__ __forceinline__ float tanhfast(float x) {
  float u = __expf(2.f * x);
  return 1.f - 2.f * fastrcp(u + 1.f);
}

// pair-combine: x + (x from lane^1), VALU-pipe via DPP quad_perm [1,0,3,2]
__device__ __forceinline__ float dppadd1(float x) {
#if __has_builtin(__builtin_amdgcn_mov_dpp)
  int y = __builtin_amdgcn_mov_dpp(__builtin_bit_cast(int, x), 0xB1, 0xF, 0xF, true);
  return x + __builtin_bit_cast(float, y);
#else
  return x + __shfl_xor(x, 1);
#endif
}

// 16B global->LDS stage. lds_base must be wave-uniform; lane writes base+l*16.
__device__ __forceinline__ void stage16(const void* g, void* lds_base, int lane) {
#if __has_builtin(__builtin_amdgcn_global_load_lds)
  (void)lane;
  __builtin_amdgcn_global_load_lds((const __attribute__((address_space(1))) void*)g,
                                   (__attribute__((address_space(3))) void*)lds_base,
                                   16, 0, 0);
#else
  *(uint4*)((char*)lds_base + lane * 16) = *(const uint4*)g;
#endif
}

// ---------------- embeddings -> fp16, K padded 160->192 ----------------
__global__ void embed_h(const int* __restrict__ wid, const int* __restrict__ pid,
                        const float* __restrict__ wl, const float* __restrict__ pl,
                        _Float16* __restrict__ dst) {
  int tid = blockIdx.x * blockDim.x + threadIdx.x;  // kTok * 24 chunks of 8 cols
  if (tid >= kTok * 24) return;
  int tok = tid / 24, c8 = tid % 24;
  h8 o;
  if (c8 < 20) {
    const float* src = (c8 < 16) ? (wl + (size_t)wid[tok] * 128 + c8 * 8)
                                 : (pl + (size_t)pid[tok] * 32 + (c8 - 16) * 8);
    float4 v0 = *(const float4*)src;
    float4 v1 = *(const float4*)(src + 4);
    o[0] = (_Float16)v0.x; o[1] = (_Float16)v0.y;
    o[2] = (_Float16)v0.z; o[3] = (_Float16)v0.w;
    o[4] = (_Float16)v1.x; o[5] = (_Float16)v1.y;
    o[6] = (_Float16)v1.z; o[7] = (_Float16)v1.w;
  } else {
    o = (h8)(_Float16)0.f;
  }
  *(h8*)(dst + (size_t)tok * 192 + c8 * 8) = o;
}

// ---------------- fp32 -> fp16 with K zero-pad ----------------
__global__ void f2h_pad(const float* __restrict__ src, _Float16* __restrict__ dst,
                        int rows, int Kin, int Kpad) {
  int per = Kpad >> 2;
  int tid = blockIdx.x * blockDim.x + threadIdx.x;
  if (tid >= rows * per) return;
  int row = tid / per, c4 = (tid % per) << 2;
  h4 o;
  if (c4 < Kin) {
    float4 v = *(const float4*)(src + (size_t)row * Kin + c4);
    o[0] = (_Float16)v.x; o[1] = (_Float16)v.y;
    o[2] = (_Float16)v.z; o[3] = (_Float16)v.w;
  } else {
    o = (h4)(_Float16)0.f;
  }
  *(h4*)(dst + (size_t)row * Kpad + c4) = o;
}

// ---------------- bias sums (bih+bhh per layer/dir) ----------------
__global__ void prep_bias(const float* __restrict__ b0, const float* __restrict__ b1,
                          const float* __restrict__ b2, const float* __restrict__ b3,
                          const float* __restrict__ b4, const float* __restrict__ b5,
                          const float* __restrict__ b6, const float* __restrict__ b7,
                          float* __restrict__ bsum) {
  int tid = blockIdx.x * blockDim.x + threadIdx.x;
  if (tid >= 4 * kG4) return;
  int grp = tid >> 10, i = tid & 1023;
  const float* x; const float* y;
  switch (grp) {
    case 0: x = b0; y = b1; break;
    case 1: x = b2; y = b3; break;
    case 2: x = b4; y = b5; break;
    default: x = b6; y = b7; break;
  }
  bsum[tid] = x[i] + y[i];
}

__global__ void concat_bias(const float* __restrict__ a, const float* __restrict__ b,
                            float* __restrict__ dst) {
  int tid = blockIdx.x * blockDim.x + threadIdx.x;
  if (tid >= kG4) return;
  dst[tid] = (tid < 512) ? a[tid] : b[tid - 512];
}

// ---------------- heads weight: W96[128][1024] = [outL|0 ; 0|routL] --------
__global__ void build_w96(const float* __restrict__ outL, const float* __restrict__ outB,
                          const float* __restrict__ routL, const float* __restrict__ routB,
                          _Float16* __restrict__ w, float* __restrict__ b) {
  int tid = blockIdx.x * blockDim.x + threadIdx.x;  // 128*1024
  if (tid >= 128 * 1024) return;
  int n = tid >> 10, k = tid & 1023;
  float v = 0.f;
  if (n < 3) { if (k < 512) v = outL[n * 512 + k]; }
  else if (n < 96) { if (k >= 512) v = routL[(size_t)(n - 3) * 512 + (k - 512)]; }
  w[tid] = (_Float16)v;
  if (k == 0) b[n] = (n < 3) ? outB[n] : (n < 96 ? routB[n - 3] : 0.f);
}

// ---------------- f16 MFMA GEMM 128x128 (xg + heads) -----------------------
// CMODE 1: fp32 xg-swizzled: col' = (col&255)*4 + (col>>8)
// CMODE 3: heads: col<3 -> out[row*3+col]; 3<=col<96 -> rout[row*93+col-3]
template <bool GATHER, int CMODE>
__global__ __launch_bounds__(256) void mfma_gemm(
    const _Float16* __restrict__ A, int lda,
    const _Float16* __restrict__ W,
    const float* __restrict__ bias,
    const _Float16* __restrict__ vsrc, const int* __restrict__ fidx,
    void* __restrict__ C, int K) {
  __shared__ _Float16 Asm[128 * 64];  // 16 KB
  __shared__ _Float16 Bsm[128 * 64];  // 16 KB
  const int tid = threadIdx.x;
  const int w = tid >> 6, l = tid & 63;
  const int wr = w >> 1, wc = w & 1;
  const int m0 = blockIdx.y * 128, n0 = blockIdx.x * 128;
  const int lrow = l & 15, lk8 = (l >> 4) << 3;
  const int stg_r = l >> 3;
  const int stg_c = (l & 7) ^ stg_r;

  f4 acc[4][4] = {};

  for (int k0 = 0; k0 < K; k0 += 64) {
#pragma unroll
    for (int ii = 0; ii < 4; ++ii) {
      const int r = w * 32 + ii * 8 + stg_r;
      const _Float16* ga;
      if (GATHER) {
        const int token = m0 + r;
        const int slot = k0 >> 9;
        const int idx = fidx[token * 12 + slot];
        ga = vsrc + ((((size_t)(token >> 8) << 8) + idx) << 9) + (k0 & 511) + (stg_c << 3);
      } else {
        ga = A + (size_t)(m0 + r) * lda + k0 + (stg_c << 3);
      }
      stage16(ga, &Asm[(size_t)(w * 32 + ii * 8) * 64], l);
      const _Float16* gb = W + (size_t)(n0 + r) * K + k0 + (stg_c << 3);
      stage16(gb, &Bsm[(size_t)(w * 32 + ii * 8) * 64], l);
    }
    __syncthreads();
#pragma unroll
    for (int kk = 0; kk < 64; kk += 32) {
      const int c0 = (kk + lk8) >> 3;
      h8 af[4], bf[4];
#pragma unroll
      for (int m = 0; m < 4; ++m) {
        const int row = wr * 64 + m * 16 + lrow;
        af[m] = *(const h8*)&Asm[row * 64 + ((c0 ^ (row & 7)) << 3)];
      }
#pragma unroll
      for (int n = 0; n < 4; ++n) {
        const int row = wc * 64 + n * 16 + lrow;
        bf[n] = *(const h8*)&Bsm[row * 64 + ((c0 ^ (row & 7)) << 3)];
      }
#pragma unroll
      for (int m = 0; m < 4; ++m)
#pragma unroll
        for (int n = 0; n < 4; ++n)
          acc[m][n] = __builtin_amdgcn_mfma_f32_16x16x32_f16(af[m], bf[n], acc[m][n], 0, 0, 0);
    }
    __syncthreads();
  }
  // epilogue: C/D layout col=lane&15, row=(lane>>4)*4+reg (m89/m91)
#pragma unroll
  for (int n = 0; n < 4; ++n) {
    const int col = n0 + wc * 64 + n * 16 + lrow;
    const float bb = bias[col];
#pragma unroll
    for (int m = 0; m < 4; ++m) {
      const int rowb = m0 + wr * 64 + m * 16 + ((l >> 4) << 2);
#pragma unroll
      for (int r = 0; r < 4; ++r) {
        float v = acc[m][n][r] + bb;
        const size_t row = rowb + r;
        if (CMODE == 1) {
          ((float*)C)[row * kG4 + ((col & 255) * 4 + (col >> 8))] = v;
        } else if (CMODE == 2) {
          ((_Float16*)C)[row * kG4 + col] = (_Float16)tanhf(v);
        } else {
          if (col < 3)       ((float*)C)[row * 3 + col] = v;
          else if (col < 96) ((float*)C)[(size_t)kTok * 3 + row * 93 + (col - 3)] = v;
        }
      }
    }
  }
}

// ---------------- gather MFMA GEMM 256x128 (hid/rhid, K=6144) --------------
// 512 threads = 8 waves in 4(M)x2(N); per wave 64x64 out. LDS A 32K + B 16K.
// Same staging/swizzle idioms as the 128-tile kernel; W panel traffic halved.
__global__ __launch_bounds__(512) void mfma_gemm_g256(
    const _Float16* __restrict__ W,
    const float* __restrict__ bias,
    const _Float16* __restrict__ vsrc, const int* __restrict__ fidx,
    _Float16* __restrict__ C, int K) {
  __shared__ _Float16 Asm[256 * 64];  // 32 KB
  __shared__ _Float16 Bsm[128 * 64];  // 16 KB
  const int tid = threadIdx.x;
  const int w = tid >> 6, l = tid & 63;
  const int wr = w >> 1, wc = w & 1;            // 4 x 2 wave grid
  const int m0 = blockIdx.y * 256, n0 = blockIdx.x * 128;
  const int lrow = l & 15, lk8 = (l >> 4) << 3;
  const int stg_r = l >> 3;
  const int stg_c = (l & 7) ^ stg_r;

  f4 acc[4][4] = {};

  for (int k0 = 0; k0 < K; k0 += 64) {
    // stage A: wave w -> rows [w*32, w*32+32)
#pragma unroll
    for (int ii = 0; ii < 4; ++ii) {
      const int token = m0 + w * 32 + ii * 8 + stg_r;
      const int slot = k0 >> 9;
      const int idx = fidx[token * 12 + slot];
      const _Float16* ga =
          vsrc + ((((size_t)(token >> 8) << 8) + idx) << 9) + (k0 & 511) + (stg_c << 3);
      stage16(ga, &Asm[(size_t)(w * 32 + ii * 8) * 64], l);
    }
    // stage B: wave w -> rows [w*16, w*16+16)
#pragma unroll
    for (int ii = 0; ii < 2; ++ii) {
      const int r = w * 16 + ii * 8 + stg_r;
      const _Float16* gb = W + (size_t)(n0 + r) * K + k0 + (stg_c << 3);
      stage16(gb, &Bsm[(size_t)(w * 16 + ii * 8) * 64], l);
    }
    __syncthreads();
#pragma unroll
    for (int kk = 0; kk < 64; kk += 32) {
      const int c0 = (kk + lk8) >> 3;
      h8 af[4], bf[4];
#pragma unroll
      for (int m = 0; m < 4; ++m) {
        const int row = wr * 64 + m * 16 + lrow;
        af[m] = *(const h8*)&Asm[row * 64 + ((c0 ^ (row & 7)) << 3)];
      }
#pragma unroll
      for (int n = 0; n < 4; ++n) {
        const int row = wc * 64 + n * 16 + lrow;
        bf[n] = *(const h8*)&Bsm[row * 64 + ((c0 ^ (row & 7)) << 3)];
      }
#pragma unroll
      for (int m = 0; m < 4; ++m)
#pragma unroll
        for (int n = 0; n < 4; ++n)
          acc[m][n] = __builtin_amdgcn_mfma_f32_16x16x32_f16(af[m], bf[n], acc[m][n], 0, 0, 0);
    }
    __syncthreads();
  }
#pragma unroll
  for (int n = 0; n < 4; ++n) {
    const int col = n0 + wc * 64 + n * 16 + lrow;
    const float bb = bias[col];
#pragma unroll
    for (int m = 0; m < 4; ++m) {
      const int rowb = m0 + wr * 64 + m * 16 + ((l >> 4) << 2);
#pragma unroll
      for (int r = 0; r < 4; ++r) {
        float v = acc[m][n][r] + bb;
        C[(size_t)(rowb + r) * kG4 + col] = (_Float16)tanhf(v);
      }
    }
  }
}

// ---------------- LSTM recurrence v6: 208 VGPR weights + swizzled LDS ------
// grid 128: dir = bid&1, row = bid>>1. 512 threads: pair (t, t^1) owns
// column c = t>>1 over k-half kh = t&1. Weights per gate: 52 pairs VGPR +
// 12 pairs LDS (96 KB, t^((t>>3)&7) swizzled -- v3 measured 0 conflicts).
// xg float4 loaded in-loop, added after DPP combine (both lanes same value).
__global__ __launch_bounds__(512, 2) void lstm_rec_kernel(
    const float* __restrict__ xg_f, const float* __restrict__ xg_b,
    const float* __restrict__ Whh_f, const float* __restrict__ Whh_b,
    _Float16* __restrict__ out /* [B][S][512] fp16 */) {
  __shared__ uint4 wlds4[12 * 512];                    // 96 KB weight slice
  __shared__ __align__(16) _Float16 hbuf[2][kH];       // double-buffered h

  const int bid = blockIdx.x;
  const int dir = bid & 1;
  const int row = bid >> 1;
  const float* xg  = dir ? xg_b : xg_f;
  const float* Whh = dir ? Whh_b : Whh_f;
  const int t = threadIdx.x;
  const int c  = t >> 1;     // column 0..255
  const int kh = t & 1;      // k-half
  const int kbase = kh * 128;
  const int tsw = t ^ ((t >> 3) & 7);   // bank-spread swizzle (restored from v3)

  // ---- one-time: weights for 4 gates of column c, k in [kbase,kbase+128) --
  h2 wv[4][52];
#pragma unroll
  for (int g = 0; g < 4; ++g) {
    const float2* wr = (const float2*)(Whh + (size_t)(g * kH + c) * kH + kbase);
#pragma unroll
    for (int p = 0; p < 52; ++p) {
      float2 f = wr[p];
      h2 a; a.x = (_Float16)f.x; a.y = (_Float16)f.y;
      wv[g][p] = a;
    }
#pragma unroll
    for (int q = 0; q < 3; ++q) {         // pairs 52..63 -> LDS
      unsigned u[4];
#pragma unroll
      for (int i = 0; i < 4; ++i) {
        float2 f = wr[52 + 4 * q + i];
        h2 a; a.x = (_Float16)f.x; a.y = (_Float16)f.y;
        u[i] = __builtin_bit_cast(unsigned, a);
      }
      wlds4[(g * 3 + q) * 512 + tsw] = make_uint4(u[0], u[1], u[2], u[3]);
    }
  }
  if (t < kH) hbuf[1][t] = (_Float16)0.f;   // step 0 reads hbuf[1]
  float c_state = 0.f;
  __syncthreads();

  const float* xgr = xg + (size_t)(row * kS) * kG4;
  const int sstep = dir ? -1 : 1;
  int s = dir ? (kS - 1) : 0;

  for (int it = 0; it < kS; ++it) {
    // current step's xg (independent of h; latency hides under the dot)
    const float4 xv = *(const float4*)(xgr + (size_t)s * kG4 + 4 * c);

    float a0 = 0.f, a1 = 0.f, a2 = 0.f, a3 = 0.f;
    const uint4* hh = ((const uint4*)hbuf[(it & 1) ^ 1]) + kh * 16;
    // VGPR-resident weight pairs (p = 0..51)
#pragma unroll
    for (int u = 0; u < 13; ++u) {
      uint4 hv = hh[u];
      h2 h0 = __builtin_bit_cast(h2, hv.x);
      h2 h1 = __builtin_bit_cast(h2, hv.y);
      h2 hx = __builtin_bit_cast(h2, hv.z);
      h2 h3 = __builtin_bit_cast(h2, hv.w);
      a0 = dot2acc(wv[0][4*u+0], h0, a0); a0 = dot2acc(wv[0][4*u+1], h1, a0);
      a0 = dot2acc(wv[0][4*u+2], hx, a0); a0 = dot2acc(wv[0][4*u+3], h3, a0);
      a1 = dot2acc(wv[1][4*u+0], h0, a1); a1 = dot2acc(wv[1][4*u+1], h1, a1);
      a1 = dot2acc(wv[1][4*u+2], hx, a1); a1 = dot2acc(wv[1][4*u+3], h3, a1);
      a2 = dot2acc(wv[2][4*u+0], h0, a2); a2 = dot2acc(wv[2][4*u+1], h1, a2);
      a2 = dot2acc(wv[2][4*u+2], hx, a2); a2 = dot2acc(wv[2][4*u+3], h3, a2);
      a3 = dot2acc(wv[3][4*u+0], h0, a3); a3 = dot2acc(wv[3][4*u+1], h1, a3);
      a3 = dot2acc(wv[3][4*u+2], hx, a3); a3 = dot2acc(wv[3][4*u+3], h3, a3);
    }
    // LDS-resident weight pairs (p = 52..63), h uint4 13..15
#pragma unroll
    for (int q = 0; q < 3; ++q) {
      uint4 hv = hh[13 + q];
      h2 h0 = __builtin_bit_cast(h2, hv.x);
      h2 h1 = __builtin_bit_cast(h2, hv.y);
      h2 hx = __builtin_bit_cast(h2, hv.z);
      h2 h3 = __builtin_bit_cast(h2, hv.w);
      uint4 w0 = wlds4[(0 * 3 + q) * 512 + tsw];
      uint4 w1 = wlds4[(1 * 3 + q) * 512 + tsw];
      uint4 w2 = wlds4[(2 * 3 + q) * 512 + tsw];
      uint4 w3 = wlds4[(3 * 3 + q) * 512 + tsw];
      a0 = dot2acc(__builtin_bit_cast(h2, w0.x), h0, a0);
      a0 = dot2acc(__builtin_bit_cast(h2, w0.y), h1, a0);
      a0 = dot2acc(__builtin_bit_cast(h2, w0.z), hx, a0);
      a0 = dot2acc(__builtin_bit_cast(h2, w0.w), h3, a0);
      a1 = dot2acc(__builtin_bit_cast(h2, w1.x), h0, a1);
      a1 = dot2acc(__builtin_bit_cast(h2, w1.y), h1, a1);
      a1 = dot2acc(__builtin_bit_cast(h2, w1.z), hx, a1);
      a1 = dot2acc(__builtin_bit_cast(h2, w1.w), h3, a1);
      a2 = dot2acc(__builtin_bit_cast(h2, w2.x), h0, a2);
      a2 = dot2acc(__builtin_bit_cast(h2, w2.y), h1, a2);
      a2 = dot2acc(__builtin_bit_cast(h2, w2.z), hx, a2);
      a2 = dot2acc(__builtin_bit_cast(h2, w2.w), h3, a2);
      a3 = dot2acc(__builtin_bit_cast(h2, w3.x), h0, a3);
      a3 = dot2acc(__builtin_bit_cast(h2, w3.y), h1, a3);
      a3 = dot2acc(__builtin_bit_cast(h2, w3.z), hx, a3);
      a3 = dot2acc(__builtin_bit_cast(h2, w3.w), h3, a3);
    }
    // combine k-halves (DPP, VALU pipe); xg added once (same value both lanes)
    float s0 = dppadd1(a0) + xv.x;
    float s1 = dppadd1(a1) + xv.y;
    float s2 = dppadd1(a2) + xv.z;
    float s3 = dppadd1(a3) + xv.w;
    // nonlinearity (redundant in both lanes; keeps c_state without exchange)
    float i_ = sigf(s0);
    float f_ = sigf(s1);
    float g_ = tanhfast(s2);
    float o_ = sigf(s3);
    c_state = f_ * c_state + i_ * g_;
    float h = o_ * tanhfast(c_state);
    if (!kh) {
      hbuf[it & 1][c] = (_Float16)h;
      out[((size_t)(row * kS + s)) * kLD + dir * kH + c] = (_Float16)h;
    }
    s += sstep;
    __syncthreads();
  }
}

// ---------------------------------------------------------------------------
extern "C" void kernel_launch(void* const* d_in, const int* in_sizes, int n_in,
                              void* d_out, int out_size, void* d_ws, size_t ws_size,
                              hipStream_t stream) {
  const int*   word_ids = (const int*)d_in[0];
  const int*   pos_ids  = (const int*)d_in[1];
  const int*   feat_idx = (const int*)d_in[2];
  const float* wlookup  = (const float*)d_in[3];
  const float* plookup  = (const float*)d_in[4];
  const float* Wih1f = (const float*)d_in[5];
  const float* Whh1f = (const float*)d_in[6];
  const float* bih1f = (const float*)d_in[7];
  const float* bhh1f = (const float*)d_in[8];
  const float* Wih1b = (const float*)d_in[9];
  const float* Whh1b = (const float*)d_in[10];
  const float* bih1b = (const float*)d_in[11];
  const float* bhh1b = (const float*)d_in[12];
  const float* Wih2f = (const float*)d_in[13];
  const float* Whh2f = (const float*)d_in[14];
  const float* bih2f = (const float*)d_in[15];
  const float* bhh2f = (const float*)d_in[16];
  const float* Wih2b = (const float*)d_in[17];
  const float* Whh2b = (const float*)d_in[18];
  const float* bih2b = (const float*)d_in[19];
  const float* bhh2b = (const float*)d_in[20];
  const float* hidLayer  = (const float*)d_in[21];
  const float* hidBias   = (const float*)d_in[22];
  const float* outLayer  = (const float*)d_in[23];
  const float* outBias   = (const float*)d_in[24];
  const float* rhidLayer = (const float*)d_in[25];
  const float* rhidBias  = (const float*)d_in[26];
  const float* routLayer = (const float*)d_in[27];
  const float* routBias  = (const float*)d_in[28];

  float* ws = (float*)d_ws;
  // workspace layout (float units; fp16 buffers counted as half-floats)
  const size_t F_IVECH = 0;
  const size_t F_XGF   = F_IVECH + (size_t)kTok * 192 / 2;
  const size_t F_XGB   = F_XGF + (size_t)kTok * kG4;         // fp32 (swizzled)
  const size_t F_V1H   = F_XGB + (size_t)kTok * kG4;
  const size_t F_V2H   = F_V1H + (size_t)kTok * kLD / 2;
  const size_t F_WHA   = F_V2H + (size_t)kTok * kLD / 2;
  const size_t F_WHB   = F_WHA + (size_t)2 * kG4 * 192 / 2;
  const size_t F_WHID  = F_WHB + (size_t)2 * kG4 * 512 / 2;
  const size_t F_BSUM  = F_WHID + (size_t)kG4 * 6144 / 2;
  const size_t F_HB    = F_BSUM + 4 * kG4;
  const size_t F_W96   = F_HB + kG4;
  const size_t F_B96   = F_W96 + (size_t)128 * kG4 / 2;
  const size_t F_END   = F_B96 + 128;
  const size_t F_HID   = F_XGF;                              // overlay after rec L2
  if (ws_size < F_END * sizeof(float)) return;

  _Float16* ivec_h = (_Float16*)(ws + F_IVECH);
  float*    xgs_f  = ws + F_XGF;
  float*    xgs_b  = ws + F_XGB;
  _Float16* vec1h  = (_Float16*)(ws + F_V1H);
  _Float16* vec2h  = (_Float16*)(ws + F_V2H);
  _Float16* whA    = (_Float16*)(ws + F_WHA);
  _Float16* whB    = (_Float16*)(ws + F_WHB);
  _Float16* whid   = (_Float16*)(ws + F_WHID);
  float*    bsum   = ws + F_BSUM;
  float*    hb     = ws + F_HB;
  _Float16* w96    = (_Float16*)(ws + F_W96);
  float*    b96    = ws + F_B96;
  _Float16* hidc_h = (_Float16*)(ws + F_HID);
  float*    outp   = (float*)d_out;

  // 1. weight/bias prep + embeddings
  prep_bias<<<16, 256, 0, stream>>>(bih1f, bhh1f, bih1b, bhh1b,
                                    bih2f, bhh2f, bih2b, bhh2b, bsum);
  concat_bias<<<4, 256, 0, stream>>>(hidBias, rhidBias, hb);
  build_w96<<<512, 256, 0, stream>>>(outLayer, outBias, routLayer, routBias, w96, b96);
  f2h_pad<<<(1024 * 48 + 255) / 256, 256, 0, stream>>>(Wih1f, whA, 1024, 160, 192);
  f2h_pad<<<(1024 * 48 + 255) / 256, 256, 0, stream>>>(Wih1b, whA + 1024 * 192, 1024, 160, 192);
  f2h_pad<<<(1024 * 128 + 255) / 256, 256, 0, stream>>>(Wih2f, whB, 1024, 512, 512);
  f2h_pad<<<(1024 * 128 + 255) / 256, 256, 0, stream>>>(Wih2b, whB + 1024 * 512, 1024, 512, 512);
  f2h_pad<<<(512 * 1536 + 255) / 256, 256, 0, stream>>>(hidLayer, whid, 512, 6144, 6144);
  f2h_pad<<<(512 * 1536 + 255) / 256, 256, 0, stream>>>(rhidLayer, whid + (size_t)512 * 6144,
                                                        512, 6144, 6144);
  embed_h<<<(kTok * 24 + 255) / 256, 256, 0, stream>>>(word_ids, pos_ids,
                                                       wlookup, plookup, ivec_h);
  // 2. layer-1 input gates (K=192, zero-padded), xg-swizzled output
  mfma_gemm<false, 1><<<dim3(8, 128), 256, 0, stream>>>(
      ivec_h, 192, whA, bsum + 0, nullptr, nullptr, xgs_f, 192);
  mfma_gemm<false, 1><<<dim3(8, 128), 256, 0, stream>>>(
      ivec_h, 192, whA + 1024 * 192, bsum + 1024, nullptr, nullptr, xgs_b, 192);
  // 3. layer-1 recurrence -> fp16
  lstm_rec_kernel<<<128, 512, 0, stream>>>(xgs_f, xgs_b, Whh1f, Whh1b, vec1h);
  // 4. layer-2 input gates (K=512), xg-swizzled output
  mfma_gemm<false, 1><<<dim3(8, 128), 256, 0, stream>>>(
      vec1h, 512, whB, bsum + 2048, nullptr, nullptr, xgs_f, 512);
  mfma_gemm<false, 1><<<dim3(8, 128), 256, 0, stream>>>(
      vec1h, 512, whB + 1024 * 512, bsum + 3072, nullptr, nullptr, xgs_b, 512);
  // 5. layer-2 recurrence -> fp16
  lstm_rec_kernel<<<128, 512, 0, stream>>>(xgs_f, xgs_b, Whh2f, Whh2b, vec2h);
  // 6. gather + hid/rhid MFMA GEMM, 256x128 tile (K=6144) -> fp16 hidc
  mfma_gemm_g256<<<dim3(8, 64), 512, 0, stream>>>(
      whid, hb, vec2h, feat_idx, hidc_h, 6144);
  // 7. heads: one MFMA GEMM, K=1024, N-tile 128 (cols 0-2 out, 3-95 rout)
  mfma_gemm<false, 3><<<dim3(1, 128), 256, 0, stream>>>(
      hidc_h, kG4, w96, b96, nullptr, nullptr, outp, kG4);
}